// Round 1
// baseline (8561.646 us; speedup 1.0000x reference)
//
#include <hip/hip_runtime.h>
#include <math.h>

#define NTOK   4096
#define DMODEL 768
#define NHEAD  12
#define DHEAD  64
#define NLAYER 4
#define DFF    3072
#define NBLK   64
#define NEGC   -10000.0f

// ---------------- block-wide sum over 256 threads ----------------
__device__ __forceinline__ float block_sum256(float v) {
  __shared__ float tmp[4];
  #pragma unroll
  for (int o = 32; o > 0; o >>= 1) v += __shfl_down(v, o, 64);
  __syncthreads();                       // protect tmp from previous use
  if ((threadIdx.x & 63) == 0) tmp[threadIdx.x >> 6] = v;
  __syncthreads();
  return tmp[0] + tmp[1] + tmp[2] + tmp[3];
}

// ---------------- embedding + layernorm ----------------
__global__ __launch_bounds__(256) void embed_ln_kernel(
    const int* __restrict__ ids, const float* __restrict__ emb_word,
    const float* __restrict__ emb_pos, const float* __restrict__ g,
    const float* __restrict__ b, float* __restrict__ x)
{
  const int n = blockIdx.x;
  const int tid = threadIdx.x;
  const int id = ids[n];
  float v[3];
  #pragma unroll
  for (int j = 0; j < 3; ++j) {
    int d = tid + j * 256;
    v[j] = emb_word[(size_t)id * DMODEL + d] + emb_pos[(size_t)n * DMODEL + d];
  }
  float mu = block_sum256(v[0] + v[1] + v[2]) * (1.0f / DMODEL);
  float var = 0.f;
  #pragma unroll
  for (int j = 0; j < 3; ++j) { float t = v[j] - mu; var += t * t; }
  var = block_sum256(var) * (1.0f / DMODEL);
  float rs = rsqrtf(var + 1e-5f);
  #pragma unroll
  for (int j = 0; j < 3; ++j) {
    int d = tid + j * 256;
    x[(size_t)n * DMODEL + d] = (v[j] - mu) * rs * g[d] + b[d];
  }
}

// ---------------- residual add + layernorm ----------------
__global__ __launch_bounds__(256) void add_ln_kernel(
    const float* __restrict__ xin, const float* __restrict__ o,
    const float* __restrict__ g, const float* __restrict__ b,
    float* __restrict__ dst)
{
  const int n = blockIdx.x;
  const int tid = threadIdx.x;
  float v[3];
  #pragma unroll
  for (int j = 0; j < 3; ++j) {
    int d = tid + j * 256;
    v[j] = xin[(size_t)n * DMODEL + d] + o[(size_t)n * DMODEL + d];
  }
  float mu = block_sum256(v[0] + v[1] + v[2]) * (1.0f / DMODEL);
  float var = 0.f;
  #pragma unroll
  for (int j = 0; j < 3; ++j) { float t = v[j] - mu; var += t * t; }
  var = block_sum256(var) * (1.0f / DMODEL);
  float rs = rsqrtf(var + 1e-5f);
  #pragma unroll
  for (int j = 0; j < 3; ++j) {
    int d = tid + j * 256;
    dst[(size_t)n * DMODEL + d] = (v[j] - mu) * rs * g[d] + b[d];
  }
}

// ---------------- fp32 tiled GEMM: C = A(MxK) @ W(KxN) + bias, opt. GELU ----------------
// 128x128 tile, TK=8, 256 threads, 8x8 per thread.
__global__ __launch_bounds__(256) void gemm_kernel(
    const float* __restrict__ A, const float* __restrict__ W,
    const float* __restrict__ bias, float* __restrict__ C,
    int Mdim, int Ndim, int Kdim, int do_gelu)
{
  __shared__ float As[8][128];   // transposed A tile: As[k][m]
  __shared__ float Bs[8][128];   // Bs[k][n]
  const int bm = blockIdx.x * 128;
  const int bn = blockIdx.y * 128;
  const int tid = threadIdx.x;
  const int tr = (tid >> 4) << 3;   // row offset in tile (0..120)
  const int tc = (tid & 15) << 3;   // col offset in tile

  float acc[8][8];
  #pragma unroll
  for (int i = 0; i < 8; ++i)
    #pragma unroll
    for (int j = 0; j < 8; ++j) acc[i][j] = 0.f;

  const int ar = tid >> 1;          // 0..127
  const int ak = (tid & 1) << 2;    // 0 or 4
  const int bk = tid >> 5;          // 0..7
  const int bc = (tid & 31) << 2;   // 0..124

  for (int k0 = 0; k0 < Kdim; k0 += 8) {
    float4 av = *(const float4*)(A + (size_t)(bm + ar) * Kdim + k0 + ak);
    float4 bv = *(const float4*)(W + (size_t)(k0 + bk) * Ndim + bn + bc);
    As[ak + 0][ar] = av.x; As[ak + 1][ar] = av.y;
    As[ak + 2][ar] = av.z; As[ak + 3][ar] = av.w;
    *(float4*)(&Bs[bk][bc]) = bv;
    __syncthreads();
    #pragma unroll
    for (int kk = 0; kk < 8; ++kk) {
      float4 a0 = *(const float4*)&As[kk][tr];
      float4 a1 = *(const float4*)&As[kk][tr + 4];
      float4 b0 = *(const float4*)&Bs[kk][tc];
      float4 b1 = *(const float4*)&Bs[kk][tc + 4];
      float aa[8] = {a0.x, a0.y, a0.z, a0.w, a1.x, a1.y, a1.z, a1.w};
      float bb[8] = {b0.x, b0.y, b0.z, b0.w, b1.x, b1.y, b1.z, b1.w};
      #pragma unroll
      for (int i = 0; i < 8; ++i)
        #pragma unroll
        for (int j = 0; j < 8; ++j)
          acc[i][j] = fmaf(aa[i], bb[j], acc[i][j]);
    }
    __syncthreads();
  }

  #pragma unroll
  for (int i = 0; i < 8; ++i) {
    #pragma unroll
    for (int j = 0; j < 8; ++j) {
      float vv = acc[i][j] + bias[bn + tc + j];
      if (do_gelu) vv = 0.5f * vv * (1.f + erff(vv * 0.70710678118654752f));
      acc[i][j] = vv;
    }
    *(float4*)(C + (size_t)(bm + tr + i) * Ndim + bn + tc) =
        make_float4(acc[i][0], acc[i][1], acc[i][2], acc[i][3]);
    *(float4*)(C + (size_t)(bm + tr + i) * Ndim + bn + tc + 4) =
        make_float4(acc[i][4], acc[i][5], acc[i][6], acc[i][7]);
  }
}

// ---------------- BigBird attention, one WG per (head, query-block) ----------------
// q,k,v,out are (N, D) fp32, head h occupies cols [h*64, h*64+64).
__global__ __launch_bounds__(256) void attn_kernel(
    const float* __restrict__ qg, const float* __restrict__ kg,
    const float* __restrict__ vg, const float* __restrict__ mask,
    const int* __restrict__ rand_attn, float* __restrict__ outp)
{
  const int h = blockIdx.x;
  const int qi = blockIdx.y;
  const int tid = threadIdx.x;

  __shared__ float QT[64][68];   // Q transposed: QT[d][q]   (16B-aligned rows)
  __shared__ float KV[64][68];   // K phase: KV[d][k] (transposed); V phase: KV[k][d]
  __shared__ float Ss[64][65];   // scores/probs: Ss[q][k]
  __shared__ float mrow[64], lrow[64], alph[64];
  __shared__ int slist[64];
  __shared__ int snb;

  // load Q block transposed
  for (int e = tid; e < 4096; e += 256) {
    int r = e >> 6, c = e & 63;
    QT[c][r] = qg[(size_t)(qi * 64 + r) * DMODEL + h * 64 + c];
  }
  if (tid < 64) { mrow[tid] = -1e30f; lrow[tid] = 0.f; }
  if (tid == 0) {
    int nb;
    if (qi == 0 || qi == 63) {
      nb = 64;
      for (int j = 0; j < 64; ++j) slist[j] = j;
    } else {
      const int* ra = rand_attn + ((size_t)h * 62 + (qi - 1)) * 3;
      if (qi == 1)       { slist[0] = 0; slist[1] = 1;  slist[2] = 2;  slist[3] = 63; }
      else if (qi == 62) { slist[0] = 0; slist[1] = 61; slist[2] = 62; slist[3] = 63; }
      else               { slist[0] = 0; slist[1] = qi - 1; slist[2] = qi; slist[3] = qi + 1; }
      slist[4] = ra[0]; slist[5] = ra[1]; slist[6] = ra[2];
      nb = 7;
      if (qi >= 2 && qi <= 61) { slist[7] = 63; nb = 8; }
    }
    snb = nb;
  }
  __syncthreads();
  const int nb = snb;
  const int ty = tid >> 4, tx = tid & 15;

  float oacc[4][4];
  #pragma unroll
  for (int i = 0; i < 4; ++i)
    #pragma unroll
    for (int j = 0; j < 4; ++j) oacc[i][j] = 0.f;

  for (int bi = 0; bi < nb; ++bi) {
    const int kb = slist[bi];
    // load K block transposed into KV[d][k]
    for (int e = tid; e < 4096; e += 256) {
      int r = e >> 6, c = e & 63;
      KV[c][r] = kg[(size_t)(kb * 64 + r) * DMODEL + h * 64 + c];
    }
    __syncthreads();

    // S = Q @ K^T * sc + to-mask
    float sacc[4][4];
    #pragma unroll
    for (int i = 0; i < 4; ++i)
      #pragma unroll
      for (int j = 0; j < 4; ++j) sacc[i][j] = 0.f;
    #pragma unroll 4
    for (int d = 0; d < 64; ++d) {
      float4 q4 = *(const float4*)&QT[d][ty * 4];
      float4 k4 = *(const float4*)&KV[d][tx * 4];
      float qa[4] = {q4.x, q4.y, q4.z, q4.w};
      float ka[4] = {k4.x, k4.y, k4.z, k4.w};
      #pragma unroll
      for (int i = 0; i < 4; ++i)
        #pragma unroll
        for (int j = 0; j < 4; ++j)
          sacc[i][j] = fmaf(qa[i], ka[j], sacc[i][j]);
    }
    #pragma unroll
    for (int i = 0; i < 4; ++i)
      #pragma unroll
      for (int j = 0; j < 4; ++j) {
        float msk = mask[kb * 64 + tx * 4 + j];
        Ss[ty * 4 + i][tx * 4 + j] = sacc[i][j] * 0.125f + (1.f - msk) * NEGC;
      }
    __syncthreads();

    // load V (natural layout) into KV[k][d]; wave0 does online-softmax meanwhile
    for (int e = tid; e < 4096; e += 256) {
      int r = e >> 6, c = e & 63;
      KV[r][c] = vg[(size_t)(kb * 64 + r) * DMODEL + h * 64 + c];
    }
    if (tid < 64) {
      float mold = mrow[tid];
      float mx = mold;
      #pragma unroll 8
      for (int kk = 0; kk < 64; ++kk) mx = fmaxf(mx, Ss[tid][kk]);
      float al = __expf(mold - mx);
      float sum = 0.f;
      #pragma unroll 8
      for (int kk = 0; kk < 64; ++kk) {
        float p = __expf(Ss[tid][kk] - mx);
        Ss[tid][kk] = p;
        sum += p;
      }
      mrow[tid] = mx;
      lrow[tid] = lrow[tid] * al + sum;
      alph[tid] = al;
    }
    __syncthreads();

    // O = O*alpha + P @ V
    float av[4];
    #pragma unroll
    for (int i = 0; i < 4; ++i) av[i] = alph[ty * 4 + i];
    #pragma unroll
    for (int i = 0; i < 4; ++i)
      #pragma unroll
      for (int j = 0; j < 4; ++j) oacc[i][j] *= av[i];
    #pragma unroll 4
    for (int kk = 0; kk < 64; ++kk) {
      float4 v4 = *(const float4*)&KV[kk][tx * 4];
      float vv[4] = {v4.x, v4.y, v4.z, v4.w};
      #pragma unroll
      for (int i = 0; i < 4; ++i) {
        float p = Ss[ty * 4 + i][kk];
        #pragma unroll
        for (int j = 0; j < 4; ++j)
          oacc[i][j] = fmaf(p, vv[j], oacc[i][j]);
      }
    }
    __syncthreads();   // protect KV/Ss before next iteration
  }

  // epilogue: divide by l, apply from-mask, store
  #pragma unroll
  for (int i = 0; i < 4; ++i) {
    int r = qi * 64 + ty * 4 + i;
    float sc2 = mask[r] / lrow[ty * 4 + i];
    *(float4*)(outp + (size_t)r * DMODEL + h * 64 + tx * 4) =
        make_float4(oacc[i][0] * sc2, oacc[i][1] * sc2,
                    oacc[i][2] * sc2, oacc[i][3] * sc2);
  }
}

// ---------------- driver ----------------
extern "C" void kernel_launch(void* const* d_in, const int* in_sizes, int n_in,
                              void* d_out, int out_size, void* d_ws, size_t ws_size,
                              hipStream_t stream)
{
  const int*   ids      = (const int*)  d_in[0];
  const float* mask     = (const float*)d_in[1];
  const int*   rand_att = (const int*)  d_in[2];
  const float* emb_word = (const float*)d_in[3];
  const float* emb_pos  = (const float*)d_in[4];
  const float* eg       = (const float*)d_in[5];
  const float* eb       = (const float*)d_in[6];
  const float* Wq = (const float*)d_in[7];
  const float* bq = (const float*)d_in[8];
  const float* Wk = (const float*)d_in[9];
  const float* bk = (const float*)d_in[10];
  const float* Wv = (const float*)d_in[11];
  const float* bv = (const float*)d_in[12];
  const float* Wo = (const float*)d_in[13];
  const float* bo = (const float*)d_in[14];
  const float* ln1g = (const float*)d_in[15];
  const float* ln1b = (const float*)d_in[16];
  const float* W1 = (const float*)d_in[17];
  const float* bf1 = (const float*)d_in[18];
  const float* W2 = (const float*)d_in[19];
  const float* bf2 = (const float*)d_in[20];
  const float* ln2g = (const float*)d_in[21];
  const float* ln2b = (const float*)d_in[22];

  const size_t ND = (size_t)NTOK * DMODEL;
  float* x   = (float*)d_ws;
  float* qb  = x   + ND;
  float* kb2 = qb  + ND;
  float* vb2 = kb2 + ND;
  float* ab  = vb2 + ND;
  float* fb  = ab  + ND;      // NTOK x DFF
  float* tb  = qb;            // GEMM temp aliases q (free during proj/FFN)

  embed_ln_kernel<<<NTOK, 256, 0, stream>>>(ids, emb_word, emb_pos, eg, eb, x);

  dim3 gDD(NTOK / 128, DMODEL / 128);
  dim3 gDF(NTOK / 128, DFF / 128);

  for (int l = 0; l < NLAYER; ++l) {
    const float* Wq_l = Wq + (size_t)l * DMODEL * DMODEL;
    const float* Wk_l = Wk + (size_t)l * DMODEL * DMODEL;
    const float* Wv_l = Wv + (size_t)l * DMODEL * DMODEL;
    const float* Wo_l = Wo + (size_t)l * DMODEL * DMODEL;
    const float* W1_l = W1 + (size_t)l * DMODEL * DFF;
    const float* W2_l = W2 + (size_t)l * DFF * DMODEL;
    const float* bq_l = bq + (size_t)l * DMODEL;
    const float* bk_l = bk + (size_t)l * DMODEL;
    const float* bv_l = bv + (size_t)l * DMODEL;
    const float* bo_l = bo + (size_t)l * DMODEL;
    const float* b1_l = bf1 + (size_t)l * DFF;
    const float* b2_l = bf2 + (size_t)l * DMODEL;
    const float* g1_l = ln1g + (size_t)l * DMODEL;
    const float* be1_l = ln1b + (size_t)l * DMODEL;
    const float* g2_l = ln2g + (size_t)l * DMODEL;
    const float* be2_l = ln2b + (size_t)l * DMODEL;

    gemm_kernel<<<gDD, 256, 0, stream>>>(x, Wq_l, bq_l, qb, NTOK, DMODEL, DMODEL, 0);
    gemm_kernel<<<gDD, 256, 0, stream>>>(x, Wk_l, bk_l, kb2, NTOK, DMODEL, DMODEL, 0);
    gemm_kernel<<<gDD, 256, 0, stream>>>(x, Wv_l, bv_l, vb2, NTOK, DMODEL, DMODEL, 0);

    attn_kernel<<<dim3(NHEAD, NBLK), 256, 0, stream>>>(qb, kb2, vb2, mask, rand_att, ab);

    gemm_kernel<<<gDD, 256, 0, stream>>>(ab, Wo_l, bo_l, tb, NTOK, DMODEL, DMODEL, 0);
    add_ln_kernel<<<NTOK, 256, 0, stream>>>(x, tb, g1_l, be1_l, x);

    gemm_kernel<<<gDF, 256, 0, stream>>>(x, W1_l, b1_l, fb, NTOK, DFF, DMODEL, 1);
    gemm_kernel<<<gDD, 256, 0, stream>>>(fb, W2_l, b2_l, tb, NTOK, DMODEL, DFF, 0);
    add_ln_kernel<<<NTOK, 256, 0, stream>>>(x, tb, g2_l, be2_l,
                                            (l == NLAYER - 1) ? (float*)d_out : x);
  }
}

// Round 2
// 2734.078 us; speedup vs baseline: 3.1315x; 3.1315x over previous
//
#include <hip/hip_runtime.h>
#include <hip/hip_bf16.h>
#include <math.h>

#define NTOK   4096
#define DMODEL 768
#define NHEAD  12
#define DHEAD  64
#define NLAYER 4
#define DFF    3072
#define NBLK   64
#define NEGC   -10000.0f

using frag8 = __attribute__((ext_vector_type(8))) short;   // 8 bf16
using f32x4 = __attribute__((ext_vector_type(4))) float;

// ---------------- block-wide sum over 256 threads ----------------
__device__ __forceinline__ float block_sum256(float v) {
  __shared__ float tmp[4];
  #pragma unroll
  for (int o = 32; o > 0; o >>= 1) v += __shfl_down(v, o, 64);
  __syncthreads();
  if ((threadIdx.x & 63) == 0) tmp[threadIdx.x >> 6] = v;
  __syncthreads();
  return tmp[0] + tmp[1] + tmp[2] + tmp[3];
}

// ---------------- embedding + layernorm (emit fp32 + bf16) ----------------
__global__ __launch_bounds__(256) void embed_ln_kernel(
    const int* __restrict__ ids, const float* __restrict__ emb_word,
    const float* __restrict__ emb_pos, const float* __restrict__ g,
    const float* __restrict__ b, float* __restrict__ x,
    __hip_bfloat16* __restrict__ xb)
{
  const int n = blockIdx.x;
  const int tid = threadIdx.x;
  const int id = ids[n];
  float v[3];
  #pragma unroll
  for (int j = 0; j < 3; ++j) {
    int d = tid + j * 256;
    v[j] = emb_word[(size_t)id * DMODEL + d] + emb_pos[(size_t)n * DMODEL + d];
  }
  float mu = block_sum256(v[0] + v[1] + v[2]) * (1.0f / DMODEL);
  float var = 0.f;
  #pragma unroll
  for (int j = 0; j < 3; ++j) { float t = v[j] - mu; var += t * t; }
  var = block_sum256(var) * (1.0f / DMODEL);
  float rs = rsqrtf(var + 1e-5f);
  #pragma unroll
  for (int j = 0; j < 3; ++j) {
    int d = tid + j * 256;
    float o = (v[j] - mu) * rs * g[d] + b[d];
    x[(size_t)n * DMODEL + d] = o;
    xb[(size_t)n * DMODEL + d] = (__hip_bfloat16)o;
  }
}

// ---------------- residual add + layernorm (emit fp32 + bf16) ----------------
__global__ __launch_bounds__(256) void add_ln_kernel(
    const float* __restrict__ xin, const float* __restrict__ o,
    const float* __restrict__ g, const float* __restrict__ b,
    float* __restrict__ dst, __hip_bfloat16* __restrict__ dstb)
{
  const int n = blockIdx.x;
  const int tid = threadIdx.x;
  float v[3];
  #pragma unroll
  for (int j = 0; j < 3; ++j) {
    int d = tid + j * 256;
    v[j] = xin[(size_t)n * DMODEL + d] + o[(size_t)n * DMODEL + d];
  }
  float mu = block_sum256(v[0] + v[1] + v[2]) * (1.0f / DMODEL);
  float var = 0.f;
  #pragma unroll
  for (int j = 0; j < 3; ++j) { float t = v[j] - mu; var += t * t; }
  var = block_sum256(var) * (1.0f / DMODEL);
  float rs = rsqrtf(var + 1e-5f);
  #pragma unroll
  for (int j = 0; j < 3; ++j) {
    int d = tid + j * 256;
    float ov = (v[j] - mu) * rs * g[d] + b[d];
    dst[(size_t)n * DMODEL + d] = ov;
    dstb[(size_t)n * DMODEL + d] = (__hip_bfloat16)ov;
  }
}

// ---------------- weight convert + transpose: W(K,N) fp32 -> WT(N,K) bf16 ----------------
__global__ __launch_bounds__(256) void transpose_w_kernel(
    const float* __restrict__ W, __hip_bfloat16* __restrict__ WT, int K, int N)
{
  __shared__ float tile[32][33];
  const int n0 = blockIdx.x * 32;
  const int k0 = blockIdx.y * 32;
  const int c = threadIdx.x & 31;
  const int r0 = threadIdx.x >> 5;    // 0..7
  #pragma unroll
  for (int i = 0; i < 4; ++i) {
    int r = r0 + i * 8;
    tile[r][c] = W[(size_t)(k0 + r) * N + n0 + c];
  }
  __syncthreads();
  #pragma unroll
  for (int i = 0; i < 4; ++i) {
    int r = r0 + i * 8;
    WT[(size_t)(n0 + r) * K + k0 + c] = (__hip_bfloat16)tile[c][r];
  }
}

// ---------------- pack fused QKV bias (2304) ----------------
__global__ __launch_bounds__(256) void pack_bias_kernel(
    const float* __restrict__ bq, const float* __restrict__ bk,
    const float* __restrict__ bv, float* __restrict__ dst)
{
  int t = blockIdx.x * 256 + threadIdx.x;
  if (t < 3 * DMODEL)
    dst[t] = (t < DMODEL) ? bq[t] : (t < 2 * DMODEL ? bk[t - DMODEL] : bv[t - 2 * DMODEL]);
}

// ---------------- bf16 MFMA GEMM: C(M,N) = A(M,K) @ BT(N,K)^T + bias ----------------
// 128x128 tile, BK=32, 256 thr (4 waves, 2x2 of 64x64), 16x16x32 MFMA.
// LDS rows padded to 40 bf16 (80 B) -> 2-way-only bank aliasing on b128 frag reads.
__global__ __launch_bounds__(256) void gemm_bf16_kernel(
    const __hip_bfloat16* __restrict__ A,
    const __hip_bfloat16* __restrict__ BT,
    const float* __restrict__ bias,
    float* __restrict__ Cf,            // fp32 out (or null)
    __hip_bfloat16* __restrict__ Cb,   // bf16 out (or null)
    int Kdim, int ldC, int do_gelu)
{
  __shared__ __hip_bfloat16 Als[128 * 40];
  __shared__ __hip_bfloat16 Bls[128 * 40];
  const int tid = threadIdx.x;
  const int bm = blockIdx.x * 128;
  const int bn = blockIdx.y * 128;

  const int wave = tid >> 6, lane = tid & 63;
  const int wm = (wave >> 1) * 64, wn = (wave & 1) * 64;
  const int lm = lane & 15, quad = lane >> 4;

  f32x4 acc[4][4];
  #pragma unroll
  for (int i = 0; i < 4; ++i)
    #pragma unroll
    for (int j = 0; j < 4; ++j)
      acc[i][j] = (f32x4){0.f, 0.f, 0.f, 0.f};

  for (int k0 = 0; k0 < Kdim; k0 += 32) {
    uint4 av[2], bv[2];
    #pragma unroll
    for (int i = 0; i < 2; ++i) {
      int lin = i * 256 + tid;
      int row = lin >> 2, kc = (lin & 3) << 3;
      av[i] = *(const uint4*)(A  + (size_t)(bm + row) * Kdim + k0 + kc);
      bv[i] = *(const uint4*)(BT + (size_t)(bn + row) * Kdim + k0 + kc);
    }
    __syncthreads();   // previous tile's frags consumed
    #pragma unroll
    for (int i = 0; i < 2; ++i) {
      int lin = i * 256 + tid;
      int row = lin >> 2, kc = (lin & 3) << 3;
      *(uint4*)(Als + row * 40 + kc) = av[i];
      *(uint4*)(Bls + row * 40 + kc) = bv[i];
    }
    __syncthreads();
    frag8 afr[4], bfr[4];
    #pragma unroll
    for (int t = 0; t < 4; ++t) {
      afr[t] = *(const frag8*)(Als + (wm + t * 16 + lm) * 40 + quad * 8);
      bfr[t] = *(const frag8*)(Bls + (wn + t * 16 + lm) * 40 + quad * 8);
    }
    #pragma unroll
    for (int mt = 0; mt < 4; ++mt)
      #pragma unroll
      for (int nt = 0; nt < 4; ++nt)
        acc[mt][nt] = __builtin_amdgcn_mfma_f32_16x16x32_bf16(
            afr[mt], bfr[nt], acc[mt][nt], 0, 0, 0);
  }

  #pragma unroll
  for (int mt = 0; mt < 4; ++mt)
    #pragma unroll
    for (int nt = 0; nt < 4; ++nt)
      #pragma unroll
      for (int r = 0; r < 4; ++r) {
        int row = bm + wm + mt * 16 + quad * 4 + r;
        int col = bn + wn + nt * 16 + lm;
        float v = acc[mt][nt][r] + bias[col];
        if (do_gelu) v = 0.5f * v * (1.f + erff(v * 0.70710678118654752f));
        if (Cf) Cf[(size_t)row * ldC + col] = v;
        if (Cb) Cb[(size_t)row * ldC + col] = (__hip_bfloat16)v;
      }
}

// ---------------- BigBird attention, balanced work items ----------------
// grid (12, 78): item<8 -> qi=0 chunk item; item<70 -> qi=item-7; else qi=63 chunk item-70.
// Global rows split into 8 chunks of 8 key-blocks; partials (m,l,O) to scratch.
__global__ __launch_bounds__(256) void attn_kernel(
    const float* __restrict__ qkv, const float* __restrict__ mask,
    const int* __restrict__ rand_attn, __hip_bfloat16* __restrict__ outp,
    float* __restrict__ Mpart, float* __restrict__ Lpart, float* __restrict__ Opart)
{
  const int h = blockIdx.x;
  const int item = blockIdx.y;
  const int tid = threadIdx.x;

  int qi, chunk;
  if (item < 8)       { qi = 0;        chunk = item; }
  else if (item < 70) { qi = item - 7; chunk = -1; }
  else                { qi = 63;       chunk = item - 70; }

  __shared__ float QT[64][68];
  __shared__ float KV[64][68];
  __shared__ float Ss[64][65];
  __shared__ float mrow[64], lrow[64], alph[64];
  __shared__ int slist[8];
  __shared__ int snb;

  const float* qg = qkv;
  const float* kg = qkv + DMODEL;
  const float* vg = qkv + 2 * DMODEL;
  const int ldq = 3 * DMODEL;

  for (int e = tid; e < 4096; e += 256) {
    int r = e >> 6, c = e & 63;
    QT[c][r] = qg[(size_t)(qi * 64 + r) * ldq + h * 64 + c];
  }
  if (tid < 64) { mrow[tid] = -1e30f; lrow[tid] = 0.f; }
  if (tid == 0) {
    if (chunk >= 0) {
      for (int j = 0; j < 8; ++j) slist[j] = chunk * 8 + j;
      snb = 8;
    } else {
      const int* ra = rand_attn + ((size_t)h * 62 + (qi - 1)) * 3;
      if (qi == 1)       { slist[0] = 0; slist[1] = 1;  slist[2] = 2;  slist[3] = 63; }
      else if (qi == 62) { slist[0] = 0; slist[1] = 61; slist[2] = 62; slist[3] = 63; }
      else               { slist[0] = 0; slist[1] = qi - 1; slist[2] = qi; slist[3] = qi + 1; }
      slist[4] = ra[0]; slist[5] = ra[1]; slist[6] = ra[2];
      int nb = 7;
      if (qi >= 2 && qi <= 61) { slist[7] = 63; nb = 8; }
      snb = nb;
    }
  }
  __syncthreads();
  const int nb = snb;
  const int ty = tid >> 4, tx = tid & 15;

  float oacc[4][4];
  #pragma unroll
  for (int i = 0; i < 4; ++i)
    #pragma unroll
    for (int j = 0; j < 4; ++j) oacc[i][j] = 0.f;

  for (int bi = 0; bi < nb; ++bi) {
    const int kb = slist[bi];
    for (int e = tid; e < 4096; e += 256) {
      int r = e >> 6, c = e & 63;
      KV[c][r] = kg[(size_t)(kb * 64 + r) * ldq + h * 64 + c];
    }
    __syncthreads();

    float sacc[4][4];
    #pragma unroll
    for (int i = 0; i < 4; ++i)
      #pragma unroll
      for (int j = 0; j < 4; ++j) sacc[i][j] = 0.f;
    #pragma unroll 4
    for (int d = 0; d < 64; ++d) {
      float4 q4 = *(const float4*)&QT[d][ty * 4];
      float4 k4 = *(const float4*)&KV[d][tx * 4];
      float qa[4] = {q4.x, q4.y, q4.z, q4.w};
      float ka[4] = {k4.x, k4.y, k4.z, k4.w};
      #pragma unroll
      for (int i = 0; i < 4; ++i)
        #pragma unroll
        for (int j = 0; j < 4; ++j)
          sacc[i][j] = fmaf(qa[i], ka[j], sacc[i][j]);
    }
    #pragma unroll
    for (int i = 0; i < 4; ++i)
      #pragma unroll
      for (int j = 0; j < 4; ++j) {
        float msk = mask[kb * 64 + tx * 4 + j];
        Ss[ty * 4 + i][tx * 4 + j] = sacc[i][j] * 0.125f + (1.f - msk) * NEGC;
      }
    __syncthreads();

    for (int e = tid; e < 4096; e += 256) {
      int r = e >> 6, c = e & 63;
      KV[r][c] = vg[(size_t)(kb * 64 + r) * ldq + h * 64 + c];
    }
    if (tid < 64) {
      float mold = mrow[tid];
      float mx = mold;
      #pragma unroll 8
      for (int kk = 0; kk < 64; ++kk) mx = fmaxf(mx, Ss[tid][kk]);
      float al = __expf(mold - mx);
      float sum = 0.f;
      #pragma unroll 8
      for (int kk = 0; kk < 64; ++kk) {
        float p = __expf(Ss[tid][kk] - mx);
        Ss[tid][kk] = p;
        sum += p;
      }
      mrow[tid] = mx;
      lrow[tid] = lrow[tid] * al + sum;
      alph[tid] = al;
    }
    __syncthreads();

    float av[4];
    #pragma unroll
    for (int i = 0; i < 4; ++i) av[i] = alph[ty * 4 + i];
    #pragma unroll
    for (int i = 0; i < 4; ++i)
      #pragma unroll
      for (int j = 0; j < 4; ++j) oacc[i][j] *= av[i];
    #pragma unroll 4
    for (int kk = 0; kk < 64; ++kk) {
      float4 v4 = *(const float4*)&KV[kk][tx * 4];
      float vv[4] = {v4.x, v4.y, v4.z, v4.w};
      #pragma unroll
      for (int i = 0; i < 4; ++i) {
        float p = Ss[ty * 4 + i][kk];
        #pragma unroll
        for (int j = 0; j < 4; ++j)
          oacc[i][j] = fmaf(p, vv[j], oacc[i][j]);
      }
    }
    __syncthreads();
  }

  if (chunk < 0) {
    #pragma unroll
    for (int i = 0; i < 4; ++i) {
      int r = qi * 64 + ty * 4 + i;
      float sc2 = mask[r] / lrow[ty * 4 + i];
      #pragma unroll
      for (int j = 0; j < 4; ++j)
        outp[(size_t)r * DMODEL + h * 64 + tx * 4 + j] =
            (__hip_bfloat16)(oacc[i][j] * sc2);
    }
  } else {
    const int idx = (h * 2 + (qi == 63 ? 1 : 0)) * 8 + chunk;
    if (tid < 64) {
      Mpart[idx * 64 + tid] = mrow[tid];
      Lpart[idx * 64 + tid] = lrow[tid];
    }
    #pragma unroll
    for (int i = 0; i < 4; ++i)
      *(float4*)(Opart + (size_t)idx * 4096 + (ty * 4 + i) * 64 + tx * 4) =
          make_float4(oacc[i][0], oacc[i][1], oacc[i][2], oacc[i][3]);
  }
}

// ---------------- merge partials for global rows (qi 0 and 63) ----------------
__global__ __launch_bounds__(256) void attn_merge_kernel(
    const float* __restrict__ Mpart, const float* __restrict__ Lpart,
    const float* __restrict__ Opart, const float* __restrict__ mask,
    __hip_bfloat16* __restrict__ outp)
{
  const int h = blockIdx.x, side = blockIdx.y;
  const int qi = side ? 63 : 0;
  const int tid = threadIdx.x;
  const int r = tid >> 2;
  const int d0 = (tid & 3) * 16;
  const int base = (h * 2 + side) * 8;

  float mv[8], m = -1e30f;
  #pragma unroll
  for (int c = 0; c < 8; ++c) { mv[c] = Mpart[(base + c) * 64 + r]; m = fmaxf(m, mv[c]); }
  float sc[8], l = 0.f;
  #pragma unroll
  for (int c = 0; c < 8; ++c) {
    sc[c] = __expf(mv[c] - m);
    l += Lpart[(base + c) * 64 + r] * sc[c];
  }
  float o[16];
  #pragma unroll
  for (int d = 0; d < 16; ++d) o[d] = 0.f;
  #pragma unroll
  for (int c = 0; c < 8; ++c) {
    const float* Op = Opart + (size_t)(base + c) * 4096 + r * 64 + d0;
    #pragma unroll
    for (int d4 = 0; d4 < 4; ++d4) {
      float4 v4 = *(const float4*)(Op + d4 * 4);
      o[d4 * 4 + 0] += v4.x * sc[c];
      o[d4 * 4 + 1] += v4.y * sc[c];
      o[d4 * 4 + 2] += v4.z * sc[c];
      o[d4 * 4 + 3] += v4.w * sc[c];
    }
  }
  const int row = qi * 64 + r;
  float inv = mask[row] / l;
  #pragma unroll
  for (int d = 0; d < 16; ++d)
    outp[(size_t)row * DMODEL + h * 64 + d0 + d] = (__hip_bfloat16)(o[d] * inv);
}

// ---------------- driver ----------------
extern "C" void kernel_launch(void* const* d_in, const int* in_sizes, int n_in,
                              void* d_out, int out_size, void* d_ws, size_t ws_size,
                              hipStream_t stream)
{
  const int*   ids      = (const int*)  d_in[0];
  const float* mask     = (const float*)d_in[1];
  const int*   rand_att = (const int*)  d_in[2];
  const float* emb_word = (const float*)d_in[3];
  const float* emb_pos  = (const float*)d_in[4];
  const float* eg       = (const float*)d_in[5];
  const float* eb       = (const float*)d_in[6];
  const float* Wq = (const float*)d_in[7];
  const float* bq = (const float*)d_in[8];
  const float* Wk = (const float*)d_in[9];
  const float* bk = (const float*)d_in[10];
  const float* Wv = (const float*)d_in[11];
  const float* bv = (const float*)d_in[12];
  const float* Wo = (const float*)d_in[13];
  const float* bo = (const float*)d_in[14];
  const float* ln1g = (const float*)d_in[15];
  const float* ln1b = (const float*)d_in[16];
  const float* W1 = (const float*)d_in[17];
  const float* bf1 = (const float*)d_in[18];
  const float* W2 = (const float*)d_in[19];
  const float* bf2 = (const float*)d_in[20];
  const float* ln2g = (const float*)d_in[21];
  const float* ln2b = (const float*)d_in[22];

  const size_t ND = (size_t)NTOK * DMODEL;            // 3,145,728
  float* x   = (float*)d_ws;                          // ND fp32
  __hip_bfloat16* xb = (__hip_bfloat16*)(x + ND);     // ND bf16
  float* qkv = (float*)(xb + ND);                     // 3*ND fp32 (also t + fb_b)
  float* t   = qkv;                                   // ND fp32 (alias)
  __hip_bfloat16* fb_b = (__hip_bfloat16*)(qkv + ND); // NTOK*DFF bf16 (alias)
  __hip_bfloat16* ab_b = (__hip_bfloat16*)(qkv + 3 * ND);  // ND bf16
  __hip_bfloat16* wqkvT = (__hip_bfloat16*)((float*)ab_b + ND / 2);
  __hip_bfloat16* woT  = wqkvT + (size_t)3 * DMODEL * DMODEL;
  __hip_bfloat16* w1T  = woT  + (size_t)DMODEL * DMODEL;
  __hip_bfloat16* w2T  = w1T  + (size_t)DFF * DMODEL;
  float* biasf = (float*)(w2T + (size_t)DMODEL * DFF);
  float* Mpart = biasf + 3 * DMODEL;                  // 12*2*8*64
  float* Lpart = Mpart + NHEAD * 2 * 8 * 64;
  float* Opart = Lpart + NHEAD * 2 * 8 * 64;          // 12*2*8*4096

  embed_ln_kernel<<<NTOK, 256, 0, stream>>>(ids, emb_word, emb_pos, eg, eb, x, xb);

  for (int l = 0; l < NLAYER; ++l) {
    const float* Wq_l = Wq + (size_t)l * DMODEL * DMODEL;
    const float* Wk_l = Wk + (size_t)l * DMODEL * DMODEL;
    const float* Wv_l = Wv + (size_t)l * DMODEL * DMODEL;
    const float* Wo_l = Wo + (size_t)l * DMODEL * DMODEL;
    const float* W1_l = W1 + (size_t)l * DMODEL * DFF;
    const float* W2_l = W2 + (size_t)l * DFF * DMODEL;

    dim3 g32(DMODEL / 32, DMODEL / 32);
    transpose_w_kernel<<<g32, 256, 0, stream>>>(Wq_l, wqkvT, DMODEL, DMODEL);
    transpose_w_kernel<<<g32, 256, 0, stream>>>(Wk_l, wqkvT + (size_t)DMODEL * DMODEL, DMODEL, DMODEL);
    transpose_w_kernel<<<g32, 256, 0, stream>>>(Wv_l, wqkvT + (size_t)2 * DMODEL * DMODEL, DMODEL, DMODEL);
    transpose_w_kernel<<<g32, 256, 0, stream>>>(Wo_l, woT, DMODEL, DMODEL);
    transpose_w_kernel<<<dim3(DFF / 32, DMODEL / 32), 256, 0, stream>>>(W1_l, w1T, DMODEL, DFF);
    transpose_w_kernel<<<dim3(DMODEL / 32, DFF / 32), 256, 0, stream>>>(W2_l, w2T, DFF, DMODEL);
    pack_bias_kernel<<<9, 256, 0, stream>>>(bq + (size_t)l * DMODEL, bk + (size_t)l * DMODEL,
                                            bv + (size_t)l * DMODEL, biasf);

    // fused QKV: (4096 x 2304) = xb @ [Wq|Wk|Wv]
    gemm_bf16_kernel<<<dim3(NTOK / 128, 3 * DMODEL / 128), 256, 0, stream>>>(
        xb, wqkvT, biasf, qkv, nullptr, DMODEL, 3 * DMODEL, 0);

    attn_kernel<<<dim3(NHEAD, 78), 256, 0, stream>>>(qkv, mask, rand_att, ab_b,
                                                     Mpart, Lpart, Opart);
    attn_merge_kernel<<<dim3(NHEAD, 2), 256, 0, stream>>>(Mpart, Lpart, Opart, mask, ab_b);

    gemm_bf16_kernel<<<dim3(NTOK / 128, DMODEL / 128), 256, 0, stream>>>(
        ab_b, woT, bo + (size_t)l * DMODEL, t, nullptr, DMODEL, DMODEL, 0);
    add_ln_kernel<<<NTOK, 256, 0, stream>>>(x, t, ln1g + (size_t)l * DMODEL,
                                            ln1b + (size_t)l * DMODEL, x, xb);

    gemm_bf16_kernel<<<dim3(NTOK / 128, DFF / 128), 256, 0, stream>>>(
        xb, w1T, bf1 + (size_t)l * DFF, nullptr, fb_b, DMODEL, DFF, 1);
    gemm_bf16_kernel<<<dim3(NTOK / 128, DMODEL / 128), 256, 0, stream>>>(
        fb_b, w2T, bf2 + (size_t)l * DMODEL, t, nullptr, DFF, DMODEL, 0);
    add_ln_kernel<<<NTOK, 256, 0, stream>>>(x, t, ln2g + (size_t)l * DMODEL,
                                            ln2b + (size_t)l * DMODEL,
                                            (l == NLAYER - 1) ? (float*)d_out : x, xb);
  }
}

// Round 3
// 1201.523 us; speedup vs baseline: 7.1257x; 2.2755x over previous
//
#include <hip/hip_runtime.h>
#include <hip/hip_bf16.h>
#include <math.h>

#define NTOK   4096
#define DMODEL 768
#define NHEAD  12
#define DHEAD  64
#define NLAYER 4
#define DFF    3072
#define NBLK   64
#define NEGC   -10000.0f

using frag8 = __attribute__((ext_vector_type(8))) short;   // 8 bf16
using f32x4 = __attribute__((ext_vector_type(4))) float;

typedef __attribute__((address_space(3))) void       lds_void;
typedef const __attribute__((address_space(1))) void gbl_void;

__device__ __forceinline__ void gload_lds16(const void* g, void* l) {
  __builtin_amdgcn_global_load_lds((gbl_void*)g, (lds_void*)l, 16, 0, 0);
}

// ---------------- block-wide sum over 256 threads ----------------
__device__ __forceinline__ float block_sum256(float v) {
  __shared__ float tmp[4];
  #pragma unroll
  for (int o = 32; o > 0; o >>= 1) v += __shfl_down(v, o, 64);
  __syncthreads();
  if ((threadIdx.x & 63) == 0) tmp[threadIdx.x >> 6] = v;
  __syncthreads();
  return tmp[0] + tmp[1] + tmp[2] + tmp[3];
}

// ---------------- embedding + layernorm (emit fp32 + bf16) ----------------
__global__ __launch_bounds__(256) void embed_ln_kernel(
    const int* __restrict__ ids, const float* __restrict__ emb_word,
    const float* __restrict__ emb_pos, const float* __restrict__ g,
    const float* __restrict__ b, float* __restrict__ x,
    __hip_bfloat16* __restrict__ xb)
{
  const int n = blockIdx.x;
  const int tid = threadIdx.x;
  const int id = ids[n];
  float v[3];
  #pragma unroll
  for (int j = 0; j < 3; ++j) {
    int d = tid + j * 256;
    v[j] = emb_word[(size_t)id * DMODEL + d] + emb_pos[(size_t)n * DMODEL + d];
  }
  float mu = block_sum256(v[0] + v[1] + v[2]) * (1.0f / DMODEL);
  float var = 0.f;
  #pragma unroll
  for (int j = 0; j < 3; ++j) { float t = v[j] - mu; var += t * t; }
  var = block_sum256(var) * (1.0f / DMODEL);
  float rs = rsqrtf(var + 1e-5f);
  #pragma unroll
  for (int j = 0; j < 3; ++j) {
    int d = tid + j * 256;
    float o = (v[j] - mu) * rs * g[d] + b[d];
    x[(size_t)n * DMODEL + d] = o;
    xb[(size_t)n * DMODEL + d] = (__hip_bfloat16)o;
  }
}

// ---------------- residual add + layernorm (emit fp32 + bf16) ----------------
__global__ __launch_bounds__(256) void add_ln_kernel(
    const float* __restrict__ xin, const float* __restrict__ o,
    const float* __restrict__ g, const float* __restrict__ b,
    float* __restrict__ dst, __hip_bfloat16* __restrict__ dstb)
{
  const int n = blockIdx.x;
  const int tid = threadIdx.x;
  float v[3];
  #pragma unroll
  for (int j = 0; j < 3; ++j) {
    int d = tid + j * 256;
    v[j] = xin[(size_t)n * DMODEL + d] + o[(size_t)n * DMODEL + d];
  }
  float mu = block_sum256(v[0] + v[1] + v[2]) * (1.0f / DMODEL);
  float var = 0.f;
  #pragma unroll
  for (int j = 0; j < 3; ++j) { float t = v[j] - mu; var += t * t; }
  var = block_sum256(var) * (1.0f / DMODEL);
  float rs = rsqrtf(var + 1e-5f);
  #pragma unroll
  for (int j = 0; j < 3; ++j) {
    int d = tid + j * 256;
    float ov = (v[j] - mu) * rs * g[d] + b[d];
    dst[(size_t)n * DMODEL + d] = ov;
    dstb[(size_t)n * DMODEL + d] = (__hip_bfloat16)ov;
  }
}

// ---------------- weight convert + transpose: W(K,N) fp32 -> WT(N,K) bf16 ----------------
__global__ __launch_bounds__(256) void transpose_w_kernel(
    const float* __restrict__ W, __hip_bfloat16* __restrict__ WT, int K, int N)
{
  __shared__ float tile[32][33];
  const int n0 = blockIdx.x * 32;
  const int k0 = blockIdx.y * 32;
  const int c = threadIdx.x & 31;
  const int r0 = threadIdx.x >> 5;
  #pragma unroll
  for (int i = 0; i < 4; ++i) {
    int r = r0 + i * 8;
    tile[r][c] = W[(size_t)(k0 + r) * N + n0 + c];
  }
  __syncthreads();
  #pragma unroll
  for (int i = 0; i < 4; ++i) {
    int r = r0 + i * 8;
    WT[(size_t)(n0 + r) * K + k0 + c] = (__hip_bfloat16)tile[c][r];
  }
}

// ---------------- pack fused QKV bias (2304) ----------------
__global__ __launch_bounds__(256) void pack_bias_kernel(
    const float* __restrict__ bq, const float* __restrict__ bk,
    const float* __restrict__ bv, float* __restrict__ dst)
{
  int t = blockIdx.x * 256 + threadIdx.x;
  if (t < 3 * DMODEL)
    dst[t] = (t < DMODEL) ? bq[t] : (t < 2 * DMODEL ? bk[t - DMODEL] : bv[t - 2 * DMODEL]);
}

// ---------------- bf16 MFMA GEMM, m97-style global_load_lds staging ----------------
// C(M,N) = A(M,K) @ BT(N,K)^T + bias.  128x128 tile, BK=32, 256 thr,
// 4 waves in 2x2 of 64x64, 16x16x32 MFMA. LDS tiles UNPADDED (required by
// global_load_lds lane mapping: chunk*1024B + lane*16B).
__global__ __launch_bounds__(256) void gemm_bf16_kernel(
    const __hip_bfloat16* __restrict__ A,
    const __hip_bfloat16* __restrict__ BT,
    const float* __restrict__ bias,
    float* __restrict__ Cf,            // fp32 out (or null)
    __hip_bfloat16* __restrict__ Cb,   // bf16 out (or null)
    int Kdim, int ldC, int do_gelu)
{
  __shared__ __hip_bfloat16 Als[128 * 32];
  __shared__ __hip_bfloat16 Bls[128 * 32];
  const int tid = threadIdx.x;
  const int bm = blockIdx.x * 128;
  const int bn = blockIdx.y * 128;

  const int wave = tid >> 6, lane = tid & 63;
  const int wm = (wave >> 1) * 64, wn = (wave & 1) * 64;
  const int lm = lane & 15, quad = lane >> 4;

  // staging map: inst j, chunk c = j*4+wave; lds byte = c*1024 + lane*16
  const int r0 = (0 * 4 + wave) * 16 + (lane >> 2);
  const int r1 = (1 * 4 + wave) * 16 + (lane >> 2);
  const int kc = (lane & 3) * 8;

  f32x4 acc[4][4];
  #pragma unroll
  for (int i = 0; i < 4; ++i)
    #pragma unroll
    for (int j = 0; j < 4; ++j)
      acc[i][j] = (f32x4){0.f, 0.f, 0.f, 0.f};

  for (int k0 = 0; k0 < Kdim; k0 += 32) {
    gload_lds16(A  + (size_t)(bm + r0) * Kdim + k0 + kc, Als + r0 * 32 + kc);
    gload_lds16(A  + (size_t)(bm + r1) * Kdim + k0 + kc, Als + r1 * 32 + kc);
    gload_lds16(BT + (size_t)(bn + r0) * Kdim + k0 + kc, Bls + r0 * 32 + kc);
    gload_lds16(BT + (size_t)(bn + r1) * Kdim + k0 + kc, Bls + r1 * 32 + kc);
    __syncthreads();   // drains vmcnt -> LDS tiles ready
    frag8 afr[4], bfr[4];
    #pragma unroll
    for (int t = 0; t < 4; ++t) {
      afr[t] = *(const frag8*)(Als + (wm + t * 16 + lm) * 32 + quad * 8);
      bfr[t] = *(const frag8*)(Bls + (wn + t * 16 + lm) * 32 + quad * 8);
    }
    #pragma unroll
    for (int mt = 0; mt < 4; ++mt)
      #pragma unroll
      for (int nt = 0; nt < 4; ++nt)
        acc[mt][nt] = __builtin_amdgcn_mfma_f32_16x16x32_bf16(
            afr[mt], bfr[nt], acc[mt][nt], 0, 0, 0);
    __syncthreads();   // frags consumed before next stage overwrites
  }

  #pragma unroll
  for (int mt = 0; mt < 4; ++mt)
    #pragma unroll
    for (int nt = 0; nt < 4; ++nt)
      #pragma unroll
      for (int r = 0; r < 4; ++r) {
        int row = bm + wm + mt * 16 + quad * 4 + r;
        int col = bn + wn + nt * 16 + lm;
        float v = acc[mt][nt][r] + bias[col];
        if (do_gelu) v = 0.5f * v * (1.f + erff(v * 0.70710678118654752f));
        if (Cf) Cf[(size_t)row * ldC + col] = v;
        if (Cb) Cb[(size_t)row * ldC + col] = (__hip_bfloat16)v;
      }
}

// ---------------- BigBird attention: bf16 MFMA, register online-softmax ----------------
// grid (12, 78): item<8 -> qi=0 chunk; item<70 -> qi=item-7; else qi=63 chunk.
// One WG = one 64-row Q strip; 4 waves own 16 rows each.
__global__ __launch_bounds__(256) void attn_kernel(
    const __hip_bfloat16* __restrict__ qkvb, const float* __restrict__ mask,
    const int* __restrict__ rand_attn, __hip_bfloat16* __restrict__ outp,
    float* __restrict__ Mpart, float* __restrict__ Lpart, float* __restrict__ Opart)
{
  const int h = blockIdx.x;
  const int item = blockIdx.y;
  const int tid = threadIdx.x;

  int qi, chunk;
  if (item < 8)       { qi = 0;        chunk = item; }
  else if (item < 70) { qi = item - 7; chunk = -1; }
  else                { qi = 63;       chunk = item - 70; }

  __shared__ __hip_bfloat16 Qs[64 * 72];   // [m][k], stride 72 (pad kills conflicts)
  __shared__ __hip_bfloat16 Ks[64 * 72];   // [n][k]
  __shared__ __hip_bfloat16 VTs[64 * 72];  // [d][k2]  (V transposed)
  __shared__ __hip_bfloat16 Ps[64 * 72];   // [m][k2]  (probs, A-layout for PV)
  __shared__ int slist[8];
  __shared__ int snb;

  const __hip_bfloat16* qg = qkvb;
  const __hip_bfloat16* kg = qkvb + DMODEL;
  const __hip_bfloat16* vg = qkvb + 2 * DMODEL;
  const int ldq = 3 * DMODEL;

  const int wave = tid >> 6, lane = tid & 63;
  const int wm = wave * 16;
  const int lm = lane & 15, quad = lane >> 4;

  // ---- stage Q (vec8 loads -> vec8 LDS writes) ----
  {
    int r = tid >> 2, c0 = (tid & 3) * 16;
    const __hip_bfloat16* qp = qg + (size_t)(qi * 64 + r) * ldq + h * 64 + c0;
    uint4 a = *(const uint4*)qp;
    uint4 b = *(const uint4*)(qp + 8);
    *(uint4*)(Qs + r * 72 + c0) = a;
    *(uint4*)(Qs + r * 72 + c0 + 8) = b;
  }
  if (tid == 0) {
    if (chunk >= 0) {
      for (int j = 0; j < 8; ++j) slist[j] = chunk * 8 + j;
      snb = 8;
    } else {
      const int* ra = rand_attn + ((size_t)h * 62 + (qi - 1)) * 3;
      if (qi == 1)       { slist[0] = 0; slist[1] = 1;  slist[2] = 2;  slist[3] = 63; }
      else if (qi == 62) { slist[0] = 0; slist[1] = 61; slist[2] = 62; slist[3] = 63; }
      else               { slist[0] = 0; slist[1] = qi - 1; slist[2] = qi; slist[3] = qi + 1; }
      slist[4] = ra[0]; slist[5] = ra[1]; slist[6] = ra[2];
      int nb = 7;
      if (qi >= 2 && qi <= 61) { slist[7] = 63; nb = 8; }
      snb = nb;
    }
  }
  __syncthreads();
  const int nb = snb;

  // hoisted Q A-frags (constant across key blocks)
  frag8 aq0 = *(const frag8*)(Qs + (wm + lm) * 72 + quad * 8);
  frag8 aq1 = *(const frag8*)(Qs + (wm + lm) * 72 + 32 + quad * 8);

  // online-softmax state: lane owns rows wm+quad*4+r (r=0..3)
  float mold[4], lsum[4];
  #pragma unroll
  for (int r = 0; r < 4; ++r) { mold[r] = -1e30f; lsum[r] = 0.f; }
  f32x4 oacc[4];
  #pragma unroll
  for (int t = 0; t < 4; ++t) oacc[t] = (f32x4){0.f, 0.f, 0.f, 0.f};

  const int sr = tid >> 2, sc0 = (tid & 3) * 16;   // staging coords

  for (int bi = 0; bi < nb; ++bi) {
    const int kb = slist[bi];
    // prefetch K, V, mask into registers
    const __hip_bfloat16* kp = kg + (size_t)(kb * 64 + sr) * ldq + h * 64 + sc0;
    const __hip_bfloat16* vp = vg + (size_t)(kb * 64 + sr) * ldq + h * 64 + sc0;
    uint4 kv0 = *(const uint4*)kp;
    uint4 kv1 = *(const uint4*)(kp + 8);
    uint4 vv0 = *(const uint4*)vp;
    uint4 vv1 = *(const uint4*)(vp + 8);
    float msk[4];
    #pragma unroll
    for (int t = 0; t < 4; ++t) msk[t] = mask[kb * 64 + t * 16 + lm];

    __syncthreads();   // prev iteration's frag reads done
    *(uint4*)(Ks + sr * 72 + sc0) = kv0;
    *(uint4*)(Ks + sr * 72 + sc0 + 8) = kv1;
    {
      union { uint4 u[2]; __hip_bfloat16 h16[16]; } vu;
      vu.u[0] = vv0; vu.u[1] = vv1;
      #pragma unroll
      for (int j = 0; j < 16; ++j)
        VTs[(sc0 + j) * 72 + sr] = vu.h16[j];
    }
    __syncthreads();

    // ---- S = Q @ K^T (wave's 16x64 strip) ----
    f32x4 sacc[4];
    #pragma unroll
    for (int t = 0; t < 4; ++t) sacc[t] = (f32x4){0.f, 0.f, 0.f, 0.f};
    #pragma unroll
    for (int t = 0; t < 4; ++t) {
      frag8 bk0 = *(const frag8*)(Ks + (t * 16 + lm) * 72 + quad * 8);
      frag8 bk1 = *(const frag8*)(Ks + (t * 16 + lm) * 72 + 32 + quad * 8);
      sacc[t] = __builtin_amdgcn_mfma_f32_16x16x32_bf16(aq0, bk0, sacc[t], 0, 0, 0);
      sacc[t] = __builtin_amdgcn_mfma_f32_16x16x32_bf16(aq1, bk1, sacc[t], 0, 0, 0);
    }

    // ---- register online-softmax (rows = quad*4+r, cols = t*16+lm) ----
    float xs[4][4];
    #pragma unroll
    for (int t = 0; t < 4; ++t)
      #pragma unroll
      for (int r = 0; r < 4; ++r)
        xs[t][r] = sacc[t][r] * 0.125f + (1.f - msk[t]) * NEGC;

    float al[4], psum[4];
    #pragma unroll
    for (int r = 0; r < 4; ++r) {
      float rm = fmaxf(fmaxf(xs[0][r], xs[1][r]), fmaxf(xs[2][r], xs[3][r]));
      rm = fmaxf(rm, __shfl_xor(rm, 1, 64));
      rm = fmaxf(rm, __shfl_xor(rm, 2, 64));
      rm = fmaxf(rm, __shfl_xor(rm, 4, 64));
      rm = fmaxf(rm, __shfl_xor(rm, 8, 64));
      float mnew = fmaxf(mold[r], rm);
      al[r] = __expf(mold[r] - mnew);
      float s = 0.f;
      #pragma unroll
      for (int t = 0; t < 4; ++t) {
        float p = __expf(xs[t][r] - mnew);
        xs[t][r] = p;
        s += p;
      }
      s += __shfl_xor(s, 1, 64);
      s += __shfl_xor(s, 2, 64);
      s += __shfl_xor(s, 4, 64);
      s += __shfl_xor(s, 8, 64);
      psum[r] = s;
      mold[r] = mnew;
    }
    #pragma unroll
    for (int r = 0; r < 4; ++r) lsum[r] = lsum[r] * al[r] + psum[r];
    #pragma unroll
    for (int t = 0; t < 4; ++t)
      #pragma unroll
      for (int r = 0; r < 4; ++r)
        oacc[t][r] *= al[r];

    // write P (bf16) into own strip; read back as A-frags (same wave only)
    #pragma unroll
    for (int t = 0; t < 4; ++t)
      #pragma unroll
      for (int r = 0; r < 4; ++r)
        Ps[(wm + quad * 4 + r) * 72 + t * 16 + lm] = (__hip_bfloat16)xs[t][r];

    frag8 ap0 = *(const frag8*)(Ps + (wm + lm) * 72 + quad * 8);
    frag8 ap1 = *(const frag8*)(Ps + (wm + lm) * 72 + 32 + quad * 8);
    #pragma unroll
    for (int t = 0; t < 4; ++t) {
      frag8 bv0 = *(const frag8*)(VTs + (t * 16 + lm) * 72 + quad * 8);
      frag8 bv1 = *(const frag8*)(VTs + (t * 16 + lm) * 72 + 32 + quad * 8);
      oacc[t] = __builtin_amdgcn_mfma_f32_16x16x32_bf16(ap0, bv0, oacc[t], 0, 0, 0);
      oacc[t] = __builtin_amdgcn_mfma_f32_16x16x32_bf16(ap1, bv1, oacc[t], 0, 0, 0);
    }
  }

  if (chunk < 0) {
    #pragma unroll
    for (int r = 0; r < 4; ++r) {
      int row = qi * 64 + wm + quad * 4 + r;
      float sc2 = mask[row] / lsum[r];
      #pragma unroll
      for (int t = 0; t < 4; ++t)
        outp[(size_t)row * DMODEL + h * 64 + t * 16 + lm] =
            (__hip_bfloat16)(oacc[t][r] * sc2);
    }
  } else {
    const int idx = (h * 2 + (qi == 63 ? 1 : 0)) * 8 + chunk;
    #pragma unroll
    for (int r = 0; r < 4; ++r) {
      int row = wm + quad * 4 + r;
      #pragma unroll
      for (int t = 0; t < 4; ++t)
        Opart[(size_t)idx * 4096 + row * 64 + t * 16 + lm] = oacc[t][r];
      if (lm == 0) {
        Mpart[idx * 64 + row] = mold[r];
        Lpart[idx * 64 + row] = lsum[r];
      }
    }
  }
}

// ---------------- merge partials for global rows (qi 0 and 63) ----------------
__global__ __launch_bounds__(256) void attn_merge_kernel(
    const float* __restrict__ Mpart, const float* __restrict__ Lpart,
    const float* __restrict__ Opart, const float* __restrict__ mask,
    __hip_bfloat16* __restrict__ outp)
{
  const int h = blockIdx.x, side = blockIdx.y;
  const int qi = side ? 63 : 0;
  const int tid = threadIdx.x;
  const int r = tid >> 2;
  const int d0 = (tid & 3) * 16;
  const int base = (h * 2 + side) * 8;

  float mv[8], m = -1e30f;
  #pragma unroll
  for (int c = 0; c < 8; ++c) { mv[c] = Mpart[(base + c) * 64 + r]; m = fmaxf(m, mv[c]); }
  float sc[8], l = 0.f;
  #pragma unroll
  for (int c = 0; c < 8; ++c) {
    sc[c] = __expf(mv[c] - m);
    l += Lpart[(base + c) * 64 + r] * sc[c];
  }
  float o[16];
  #pragma unroll
  for (int d = 0; d < 16; ++d) o[d] = 0.f;
  #pragma unroll
  for (int c = 0; c < 8; ++c) {
    const float* Op = Opart + (size_t)(base + c) * 4096 + r * 64 + d0;
    #pragma unroll
    for (int d4 = 0; d4 < 4; ++d4) {
      float4 v4 = *(const float4*)(Op + d4 * 4);
      o[d4 * 4 + 0] += v4.x * sc[c];
      o[d4 * 4 + 1] += v4.y * sc[c];
      o[d4 * 4 + 2] += v4.z * sc[c];
      o[d4 * 4 + 3] += v4.w * sc[c];
    }
  }
  const int row = qi * 64 + r;
  float inv = mask[row] / l;
  #pragma unroll
  for (int d = 0; d < 16; ++d)
    outp[(size_t)row * DMODEL + h * 64 + d0 + d] = (__hip_bfloat16)(o[d] * inv);
}

// ---------------- driver ----------------
extern "C" void kernel_launch(void* const* d_in, const int* in_sizes, int n_in,
                              void* d_out, int out_size, void* d_ws, size_t ws_size,
                              hipStream_t stream)
{
  const int*   ids      = (const int*)  d_in[0];
  const float* mask     = (const float*)d_in[1];
  const int*   rand_att = (const int*)  d_in[2];
  const float* emb_word = (const float*)d_in[3];
  const float* emb_pos  = (const float*)d_in[4];
  const float* eg       = (const float*)d_in[5];
  const float* eb       = (const float*)d_in[6];
  const float* Wq = (const float*)d_in[7];
  const float* bq = (const float*)d_in[8];
  const float* Wk = (const float*)d_in[9];
  const float* bk = (const float*)d_in[10];
  const float* Wv = (const float*)d_in[11];
  const float* bv = (const float*)d_in[12];
  const float* Wo = (const float*)d_in[13];
  const float* bo = (const float*)d_in[14];
  const float* ln1g = (const float*)d_in[15];
  const float* ln1b = (const float*)d_in[16];
  const float* W1 = (const float*)d_in[17];
  const float* bf1 = (const float*)d_in[18];
  const float* W2 = (const float*)d_in[19];
  const float* bf2 = (const float*)d_in[20];
  const float* ln2g = (const float*)d_in[21];
  const float* ln2b = (const float*)d_in[22];

  const size_t ND = (size_t)NTOK * DMODEL;
  float* x   = (float*)d_ws;                               // ND f32
  __hip_bfloat16* xb = (__hip_bfloat16*)(x + ND);          // ND bf16
  float* t   = (float*)(xb + ND);                          // ND f32
  __hip_bfloat16* qkvb = (__hip_bfloat16*)(t + ND);        // 3*ND bf16
  __hip_bfloat16* fb_b = qkvb + 3 * ND;                    // NTOK*DFF bf16
  __hip_bfloat16* ab_b = fb_b + (size_t)NTOK * DFF;        // ND bf16
  __hip_bfloat16* wqkvT = ab_b + ND;
  __hip_bfloat16* woT  = wqkvT + (size_t)3 * DMODEL * DMODEL;
  __hip_bfloat16* w1T  = woT  + (size_t)DMODEL * DMODEL;
  __hip_bfloat16* w2T  = w1T  + (size_t)DFF * DMODEL;
  float* biasf = (float*)(w2T + (size_t)DMODEL * DFF);
  float* Mpart = biasf + 3 * DMODEL;
  float* Lpart = Mpart + NHEAD * 2 * 8 * 64;
  float* Opart = Lpart + NHEAD * 2 * 8 * 64;               // 12*2*8*4096 f32

  embed_ln_kernel<<<NTOK, 256, 0, stream>>>(ids, emb_word, emb_pos, eg, eb, x, xb);

  for (int l = 0; l < NLAYER; ++l) {
    const float* Wq_l = Wq + (size_t)l * DMODEL * DMODEL;
    const float* Wk_l = Wk + (size_t)l * DMODEL * DMODEL;
    const float* Wv_l = Wv + (size_t)l * DMODEL * DMODEL;
    const float* Wo_l = Wo + (size_t)l * DMODEL * DMODEL;
    const float* W1_l = W1 + (size_t)l * DMODEL * DFF;
    const float* W2_l = W2 + (size_t)l * DFF * DMODEL;

    dim3 g32(DMODEL / 32, DMODEL / 32);
    transpose_w_kernel<<<g32, 256, 0, stream>>>(Wq_l, wqkvT, DMODEL, DMODEL);
    transpose_w_kernel<<<g32, 256, 0, stream>>>(Wk_l, wqkvT + (size_t)DMODEL * DMODEL, DMODEL, DMODEL);
    transpose_w_kernel<<<g32, 256, 0, stream>>>(Wv_l, wqkvT + (size_t)2 * DMODEL * DMODEL, DMODEL, DMODEL);
    transpose_w_kernel<<<g32, 256, 0, stream>>>(Wo_l, woT, DMODEL, DMODEL);
    transpose_w_kernel<<<dim3(DFF / 32, DMODEL / 32), 256, 0, stream>>>(W1_l, w1T, DMODEL, DFF);
    transpose_w_kernel<<<dim3(DMODEL / 32, DFF / 32), 256, 0, stream>>>(W2_l, w2T, DFF, DMODEL);
    pack_bias_kernel<<<9, 256, 0, stream>>>(bq + (size_t)l * DMODEL, bk + (size_t)l * DMODEL,
                                            bv + (size_t)l * DMODEL, biasf);

    // fused QKV (bf16 out only)
    gemm_bf16_kernel<<<dim3(NTOK / 128, 3 * DMODEL / 128), 256, 0, stream>>>(
        xb, wqkvT, biasf, nullptr, qkvb, DMODEL, 3 * DMODEL, 0);

    attn_kernel<<<dim3(NHEAD, 78), 256, 0, stream>>>(qkvb, mask, rand_att, ab_b,
                                                     Mpart, Lpart, Opart);
    attn_merge_kernel<<<dim3(NHEAD, 2), 256, 0, stream>>>(Mpart, Lpart, Opart, mask, ab_b);

    gemm_bf16_kernel<<<dim3(NTOK / 128, DMODEL / 128), 256, 0, stream>>>(
        ab_b, woT, bo + (size_t)l * DMODEL, t, nullptr, DMODEL, DMODEL, 0);
    add_ln_kernel<<<NTOK, 256, 0, stream>>>(x, t, ln1g + (size_t)l * DMODEL,
                                            ln1b + (size_t)l * DMODEL, x, xb);

    gemm_bf16_kernel<<<dim3(NTOK / 128, DFF / 128), 256, 0, stream>>>(
        xb, w1T, bf1 + (size_t)l * DFF, nullptr, fb_b, DMODEL, DFF, 1);
    gemm_bf16_kernel<<<dim3(NTOK / 128, DMODEL / 128), 256, 0, stream>>>(
        fb_b, w2T, bf2 + (size_t)l * DMODEL, t, nullptr, DFF, DMODEL, 0);
    add_ln_kernel<<<NTOK, 256, 0, stream>>>(x, t, ln2g + (size_t)l * DMODEL,
                                            ln2b + (size_t)l * DMODEL,
                                            (l == NLAYER - 1) ? (float*)d_out : x, xb);
  }
}

// Round 4
// 1153.771 us; speedup vs baseline: 7.4206x; 1.0414x over previous
//
#include <hip/hip_runtime.h>
#include <hip/hip_bf16.h>
#include <math.h>

#define NTOK   4096
#define DMODEL 768
#define NHEAD  12
#define DHEAD  64
#define NLAYER 4
#define DFF    3072
#define NBLK   64
#define NEGC   -10000.0f

using frag8 = __attribute__((ext_vector_type(8))) short;   // 8 bf16
using f32x4 = __attribute__((ext_vector_type(4))) float;

typedef __attribute__((address_space(3))) void       lds_void;
typedef const __attribute__((address_space(1))) void gbl_void;

__device__ __forceinline__ void gload_lds16(const void* g, void* l) {
  __builtin_amdgcn_global_load_lds((gbl_void*)g, (lds_void*)l, 16, 0, 0);
}

// ---------------- block-wide sum over 256 threads ----------------
__device__ __forceinline__ float block_sum256(float v) {
  __shared__ float tmp[4];
  #pragma unroll
  for (int o = 32; o > 0; o >>= 1) v += __shfl_down(v, o, 64);
  __syncthreads();
  if ((threadIdx.x & 63) == 0) tmp[threadIdx.x >> 6] = v;
  __syncthreads();
  return tmp[0] + tmp[1] + tmp[2] + tmp[3];
}

// ---------------- embedding + layernorm (emit fp32 + bf16) ----------------
__global__ __launch_bounds__(256) void embed_ln_kernel(
    const int* __restrict__ ids, const float* __restrict__ emb_word,
    const float* __restrict__ emb_pos, const float* __restrict__ g,
    const float* __restrict__ b, float* __restrict__ x,
    __hip_bfloat16* __restrict__ xb)
{
  const int n = blockIdx.x;
  const int tid = threadIdx.x;
  const int id = ids[n];
  float v[3];
  #pragma unroll
  for (int j = 0; j < 3; ++j) {
    int d = tid + j * 256;
    v[j] = emb_word[(size_t)id * DMODEL + d] + emb_pos[(size_t)n * DMODEL + d];
  }
  float mu = block_sum256(v[0] + v[1] + v[2]) * (1.0f / DMODEL);
  float var = 0.f;
  #pragma unroll
  for (int j = 0; j < 3; ++j) { float t = v[j] - mu; var += t * t; }
  var = block_sum256(var) * (1.0f / DMODEL);
  float rs = rsqrtf(var + 1e-5f);
  #pragma unroll
  for (int j = 0; j < 3; ++j) {
    int d = tid + j * 256;
    float o = (v[j] - mu) * rs * g[d] + b[d];
    x[(size_t)n * DMODEL + d] = o;
    xb[(size_t)n * DMODEL + d] = (__hip_bfloat16)o;
  }
}

// ---------------- residual add + layernorm (emit fp32 + bf16) ----------------
__global__ __launch_bounds__(256) void add_ln_kernel(
    const float* __restrict__ xin, const float* __restrict__ o,
    const float* __restrict__ g, const float* __restrict__ b,
    float* __restrict__ dst, __hip_bfloat16* __restrict__ dstb)
{
  const int n = blockIdx.x;
  const int tid = threadIdx.x;
  float v[3];
  #pragma unroll
  for (int j = 0; j < 3; ++j) {
    int d = tid + j * 256;
    v[j] = xin[(size_t)n * DMODEL + d] + o[(size_t)n * DMODEL + d];
  }
  float mu = block_sum256(v[0] + v[1] + v[2]) * (1.0f / DMODEL);
  float var = 0.f;
  #pragma unroll
  for (int j = 0; j < 3; ++j) { float t = v[j] - mu; var += t * t; }
  var = block_sum256(var) * (1.0f / DMODEL);
  float rs = rsqrtf(var + 1e-5f);
  #pragma unroll
  for (int j = 0; j < 3; ++j) {
    int d = tid + j * 256;
    float ov = (v[j] - mu) * rs * g[d] + b[d];
    dst[(size_t)n * DMODEL + d] = ov;
    dstb[(size_t)n * DMODEL + d] = (__hip_bfloat16)ov;
  }
}

// ---------------- weight convert + transpose: W(K,N) fp32 -> WT(N,K) bf16 ----------------
__global__ __launch_bounds__(256) void transpose_w_kernel(
    const float* __restrict__ W, __hip_bfloat16* __restrict__ WT, int K, int N)
{
  __shared__ float tile[32][33];
  const int n0 = blockIdx.x * 32;
  const int k0 = blockIdx.y * 32;
  const int c = threadIdx.x & 31;
  const int r0 = threadIdx.x >> 5;
  #pragma unroll
  for (int i = 0; i < 4; ++i) {
    int r = r0 + i * 8;
    tile[r][c] = W[(size_t)(k0 + r) * N + n0 + c];
  }
  __syncthreads();
  #pragma unroll
  for (int i = 0; i < 4; ++i) {
    int r = r0 + i * 8;
    WT[(size_t)(n0 + r) * K + k0 + c] = (__hip_bfloat16)tile[c][r];
  }
}

// ---------------- pack fused QKV bias (2304) ----------------
__global__ __launch_bounds__(256) void pack_bias_kernel(
    const float* __restrict__ bq, const float* __restrict__ bk,
    const float* __restrict__ bv, float* __restrict__ dst)
{
  int t = blockIdx.x * 256 + threadIdx.x;
  if (t < 3 * DMODEL)
    dst[t] = (t < DMODEL) ? bq[t] : (t < 2 * DMODEL ? bk[t - DMODEL] : bv[t - 2 * DMODEL]);
}

// ---------------- bf16 MFMA GEMM, double-buffered global_load_lds staging ----------------
// C(M,N) = A(M,K) @ BT(N,K)^T + bias.  128x128 tile, BK=32, 256 thr,
// 4 waves in 2x2 of 64x64, 16x16x32 MFMA. One barrier per K-step; the next
// tile's async loads are issued right after the barrier and drain during
// the current tile's MFMAs (latency hiding even at <1 WG/CU).
// LDS tiles UNPADDED (global_load_lds writes wave-uniform base + lane*16B).
__global__ __launch_bounds__(256) void gemm_bf16_kernel(
    const __hip_bfloat16* __restrict__ A,
    const __hip_bfloat16* __restrict__ BT,
    const float* __restrict__ bias,
    float* __restrict__ Cf,            // fp32 out (or null)
    __hip_bfloat16* __restrict__ Cb,   // bf16 out (or null)
    int Kdim, int ldC, int do_gelu)
{
  __shared__ __hip_bfloat16 Als[2][128 * 32];
  __shared__ __hip_bfloat16 Bls[2][128 * 32];
  const int tid = threadIdx.x;
  const int bm = blockIdx.x * 128;
  const int bn = blockIdx.y * 128;

  const int wave = tid >> 6, lane = tid & 63;
  const int wm = (wave >> 1) * 64, wn = (wave & 1) * 64;
  const int lm = lane & 15, quad = lane >> 4;

  // staging map: inst j in {0,1}; chunk c = j*4+wave; lds byte = c*1024 + lane*16
  const int r0 = (0 * 4 + wave) * 16 + (lane >> 2);
  const int r1 = (1 * 4 + wave) * 16 + (lane >> 2);
  const int kc = (lane & 3) * 8;

  const __hip_bfloat16* Ar0 = A  + (size_t)(bm + r0) * Kdim + kc;
  const __hip_bfloat16* Ar1 = A  + (size_t)(bm + r1) * Kdim + kc;
  const __hip_bfloat16* Br0 = BT + (size_t)(bn + r0) * Kdim + kc;
  const __hip_bfloat16* Br1 = BT + (size_t)(bn + r1) * Kdim + kc;

  f32x4 acc[4][4];
  #pragma unroll
  for (int i = 0; i < 4; ++i)
    #pragma unroll
    for (int j = 0; j < 4; ++j)
      acc[i][j] = (f32x4){0.f, 0.f, 0.f, 0.f};

  // prologue: stage tile 0 into buffer 0
  gload_lds16(Ar0, &Als[0][r0 * 32 + kc]);
  gload_lds16(Ar1, &Als[0][r1 * 32 + kc]);
  gload_lds16(Br0, &Bls[0][r0 * 32 + kc]);
  gload_lds16(Br1, &Bls[0][r1 * 32 + kc]);

  int p = 0;
  for (int k0 = 0; k0 < Kdim; k0 += 32, p ^= 1) {
    __syncthreads();   // drains vmcnt: buf[p] staged; lgkm: prev frag reads done
    const int kn = k0 + 32;
    if (kn < Kdim) {
      gload_lds16(Ar0 + kn, &Als[p ^ 1][r0 * 32 + kc]);
      gload_lds16(Ar1 + kn, &Als[p ^ 1][r1 * 32 + kc]);
      gload_lds16(Br0 + kn, &Bls[p ^ 1][r0 * 32 + kc]);
      gload_lds16(Br1 + kn, &Bls[p ^ 1][r1 * 32 + kc]);
    }
    frag8 afr[4], bfr[4];
    #pragma unroll
    for (int t = 0; t < 4; ++t) {
      afr[t] = *(const frag8*)(&Als[p][(wm + t * 16 + lm) * 32 + quad * 8]);
      bfr[t] = *(const frag8*)(&Bls[p][(wn + t * 16 + lm) * 32 + quad * 8]);
    }
    #pragma unroll
    for (int mt = 0; mt < 4; ++mt)
      #pragma unroll
      for (int nt = 0; nt < 4; ++nt)
        acc[mt][nt] = __builtin_amdgcn_mfma_f32_16x16x32_bf16(
            afr[mt], bfr[nt], acc[mt][nt], 0, 0, 0);
  }

  #pragma unroll
  for (int mt = 0; mt < 4; ++mt)
    #pragma unroll
    for (int nt = 0; nt < 4; ++nt)
      #pragma unroll
      for (int r = 0; r < 4; ++r) {
        int row = bm + wm + mt * 16 + quad * 4 + r;
        int col = bn + wn + nt * 16 + lm;
        float v = acc[mt][nt][r] + bias[col];
        if (do_gelu) v = 0.5f * v * (1.f + erff(v * 0.70710678118654752f));
        if (Cf) Cf[(size_t)row * ldC + col] = v;
        if (Cb) Cb[(size_t)row * ldC + col] = (__hip_bfloat16)v;
      }
}

// ---------------- BigBird attention: bf16 MFMA, register online-softmax ----------------
// grid (12, 78): item<8 -> qi=0 chunk; item<70 -> qi=item-7; else qi=63 chunk.
// One WG = one 64-row Q strip; 4 waves own 16 rows each.
__global__ __launch_bounds__(256) void attn_kernel(
    const __hip_bfloat16* __restrict__ qkvb, const float* __restrict__ mask,
    const int* __restrict__ rand_attn, __hip_bfloat16* __restrict__ outp,
    float* __restrict__ Mpart, float* __restrict__ Lpart, float* __restrict__ Opart)
{
  const int h = blockIdx.x;
  const int item = blockIdx.y;
  const int tid = threadIdx.x;

  int qi, chunk;
  if (item < 8)       { qi = 0;        chunk = item; }
  else if (item < 70) { qi = item - 7; chunk = -1; }
  else                { qi = 63;       chunk = item - 70; }

  __shared__ __hip_bfloat16 Qs[64 * 72];   // [m][k], stride 72 (pad kills conflicts)
  __shared__ __hip_bfloat16 Ks[64 * 72];   // [n][k]
  __shared__ __hip_bfloat16 VTs[64 * 72];  // [d][k2]  (V transposed)
  __shared__ __hip_bfloat16 Ps[64 * 72];   // [m][k2]  (probs, A-layout for PV)
  __shared__ int slist[8];
  __shared__ int snb;

  const __hip_bfloat16* qg = qkvb;
  const __hip_bfloat16* kg = qkvb + DMODEL;
  const __hip_bfloat16* vg = qkvb + 2 * DMODEL;
  const int ldq = 3 * DMODEL;

  const int wave = tid >> 6, lane = tid & 63;
  const int wm = wave * 16;
  const int lm = lane & 15, quad = lane >> 4;

  // ---- stage Q (vec8 loads -> vec8 LDS writes) ----
  {
    int r = tid >> 2, c0 = (tid & 3) * 16;
    const __hip_bfloat16* qp = qg + (size_t)(qi * 64 + r) * ldq + h * 64 + c0;
    uint4 a = *(const uint4*)qp;
    uint4 b = *(const uint4*)(qp + 8);
    *(uint4*)(Qs + r * 72 + c0) = a;
    *(uint4*)(Qs + r * 72 + c0 + 8) = b;
  }
  if (tid == 0) {
    if (chunk >= 0) {
      for (int j = 0; j < 8; ++j) slist[j] = chunk * 8 + j;
      snb = 8;
    } else {
      const int* ra = rand_attn + ((size_t)h * 62 + (qi - 1)) * 3;
      if (qi == 1)       { slist[0] = 0; slist[1] = 1;  slist[2] = 2;  slist[3] = 63; }
      else if (qi == 62) { slist[0] = 0; slist[1] = 61; slist[2] = 62; slist[3] = 63; }
      else               { slist[0] = 0; slist[1] = qi - 1; slist[2] = qi; slist[3] = qi + 1; }
      slist[4] = ra[0]; slist[5] = ra[1]; slist[6] = ra[2];
      int nb = 7;
      if (qi >= 2 && qi <= 61) { slist[7] = 63; nb = 8; }
      snb = nb;
    }
  }
  __syncthreads();
  const int nb = snb;

  // hoisted Q A-frags (constant across key blocks)
  frag8 aq0 = *(const frag8*)(Qs + (wm + lm) * 72 + quad * 8);
  frag8 aq1 = *(const frag8*)(Qs + (wm + lm) * 72 + 32 + quad * 8);

  // online-softmax state: lane owns rows wm+quad*4+r (r=0..3)
  float mold[4], lsum[4];
  #pragma unroll
  for (int r = 0; r < 4; ++r) { mold[r] = -1e30f; lsum[r] = 0.f; }
  f32x4 oacc[4];
  #pragma unroll
  for (int t = 0; t < 4; ++t) oacc[t] = (f32x4){0.f, 0.f, 0.f, 0.f};

  const int sr = tid >> 2, sc0 = (tid & 3) * 16;   // staging coords

  for (int bi = 0; bi < nb; ++bi) {
    const int kb = slist[bi];
    // prefetch K, V, mask into registers
    const __hip_bfloat16* kp = kg + (size_t)(kb * 64 + sr) * ldq + h * 64 + sc0;
    const __hip_bfloat16* vp = vg + (size_t)(kb * 64 + sr) * ldq + h * 64 + sc0;
    uint4 kv0 = *(const uint4*)kp;
    uint4 kv1 = *(const uint4*)(kp + 8);
    uint4 vv0 = *(const uint4*)vp;
    uint4 vv1 = *(const uint4*)(vp + 8);
    float msk[4];
    #pragma unroll
    for (int t = 0; t < 4; ++t) msk[t] = mask[kb * 64 + t * 16 + lm];

    __syncthreads();   // prev iteration's frag reads done
    *(uint4*)(Ks + sr * 72 + sc0) = kv0;
    *(uint4*)(Ks + sr * 72 + sc0 + 8) = kv1;
    {
      union { uint4 u[2]; __hip_bfloat16 h16[16]; } vu;
      vu.u[0] = vv0; vu.u[1] = vv1;
      #pragma unroll
      for (int j = 0; j < 16; ++j)
        VTs[(sc0 + j) * 72 + sr] = vu.h16[j];
    }
    __syncthreads();

    // ---- S = Q @ K^T (wave's 16x64 strip) ----
    f32x4 sacc[4];
    #pragma unroll
    for (int t = 0; t < 4; ++t) sacc[t] = (f32x4){0.f, 0.f, 0.f, 0.f};
    #pragma unroll
    for (int t = 0; t < 4; ++t) {
      frag8 bk0 = *(const frag8*)(Ks + (t * 16 + lm) * 72 + quad * 8);
      frag8 bk1 = *(const frag8*)(Ks + (t * 16 + lm) * 72 + 32 + quad * 8);
      sacc[t] = __builtin_amdgcn_mfma_f32_16x16x32_bf16(aq0, bk0, sacc[t], 0, 0, 0);
      sacc[t] = __builtin_amdgcn_mfma_f32_16x16x32_bf16(aq1, bk1, sacc[t], 0, 0, 0);
    }

    // ---- register online-softmax (rows = quad*4+r, cols = t*16+lm) ----
    float xs[4][4];
    #pragma unroll
    for (int t = 0; t < 4; ++t)
      #pragma unroll
      for (int r = 0; r < 4; ++r)
        xs[t][r] = sacc[t][r] * 0.125f + (1.f - msk[t]) * NEGC;

    float al[4], psum[4];
    #pragma unroll
    for (int r = 0; r < 4; ++r) {
      float rm = fmaxf(fmaxf(xs[0][r], xs[1][r]), fmaxf(xs[2][r], xs[3][r]));
      rm = fmaxf(rm, __shfl_xor(rm, 1, 64));
      rm = fmaxf(rm, __shfl_xor(rm, 2, 64));
      rm = fmaxf(rm, __shfl_xor(rm, 4, 64));
      rm = fmaxf(rm, __shfl_xor(rm, 8, 64));
      float mnew = fmaxf(mold[r], rm);
      al[r] = __expf(mold[r] - mnew);
      float s = 0.f;
      #pragma unroll
      for (int t = 0; t < 4; ++t) {
        float p = __expf(xs[t][r] - mnew);
        xs[t][r] = p;
        s += p;
      }
      s += __shfl_xor(s, 1, 64);
      s += __shfl_xor(s, 2, 64);
      s += __shfl_xor(s, 4, 64);
      s += __shfl_xor(s, 8, 64);
      psum[r] = s;
      mold[r] = mnew;
    }
    #pragma unroll
    for (int r = 0; r < 4; ++r) lsum[r] = lsum[r] * al[r] + psum[r];
    #pragma unroll
    for (int t = 0; t < 4; ++t)
      #pragma unroll
      for (int r = 0; r < 4; ++r)
        oacc[t][r] *= al[r];

    // write P (bf16) into own strip; read back as A-frags (same wave only)
    #pragma unroll
    for (int t = 0; t < 4; ++t)
      #pragma unroll
      for (int r = 0; r < 4; ++r)
        Ps[(wm + quad * 4 + r) * 72 + t * 16 + lm] = (__hip_bfloat16)xs[t][r];

    frag8 ap0 = *(const frag8*)(Ps + (wm + lm) * 72 + quad * 8);
    frag8 ap1 = *(const frag8*)(Ps + (wm + lm) * 72 + 32 + quad * 8);
    #pragma unroll
    for (int t = 0; t < 4; ++t) {
      frag8 bv0 = *(const frag8*)(VTs + (t * 16 + lm) * 72 + quad * 8);
      frag8 bv1 = *(const frag8*)(VTs + (t * 16 + lm) * 72 + 32 + quad * 8);
      oacc[t] = __builtin_amdgcn_mfma_f32_16x16x32_bf16(ap0, bv0, oacc[t], 0, 0, 0);
      oacc[t] = __builtin_amdgcn_mfma_f32_16x16x32_bf16(ap1, bv1, oacc[t], 0, 0, 0);
    }
  }

  if (chunk < 0) {
    #pragma unroll
    for (int r = 0; r < 4; ++r) {
      int row = qi * 64 + wm + quad * 4 + r;
      float sc2 = mask[row] / lsum[r];
      #pragma unroll
      for (int t = 0; t < 4; ++t)
        outp[(size_t)row * DMODEL + h * 64 + t * 16 + lm] =
            (__hip_bfloat16)(oacc[t][r] * sc2);
    }
  } else {
    const int idx = (h * 2 + (qi == 63 ? 1 : 0)) * 8 + chunk;
    #pragma unroll
    for (int r = 0; r < 4; ++r) {
      int row = wm + quad * 4 + r;
      #pragma unroll
      for (int t = 0; t < 4; ++t)
        Opart[(size_t)idx * 4096 + row * 64 + t * 16 + lm] = oacc[t][r];
      if (lm == 0) {
        Mpart[idx * 64 + row] = mold[r];
        Lpart[idx * 64 + row] = lsum[r];
      }
    }
  }
}

// ---------------- merge partials for global rows (qi 0 and 63) ----------------
__global__ __launch_bounds__(256) void attn_merge_kernel(
    const float* __restrict__ Mpart, const float* __restrict__ Lpart,
    const float* __restrict__ Opart, const float* __restrict__ mask,
    __hip_bfloat16* __restrict__ outp)
{
  const int h = blockIdx.x, side = blockIdx.y;
  const int qi = side ? 63 : 0;
  const int tid = threadIdx.x;
  const int r = tid >> 2;
  const int d0 = (tid & 3) * 16;
  const int base = (h * 2 + side) * 8;

  float mv[8], m = -1e30f;
  #pragma unroll
  for (int c = 0; c < 8; ++c) { mv[c] = Mpart[(base + c) * 64 + r]; m = fmaxf(m, mv[c]); }
  float sc[8], l = 0.f;
  #pragma unroll
  for (int c = 0; c < 8; ++c) {
    sc[c] = __expf(mv[c] - m);
    l += Lpart[(base + c) * 64 + r] * sc[c];
  }
  float o[16];
  #pragma unroll
  for (int d = 0; d < 16; ++d) o[d] = 0.f;
  #pragma unroll
  for (int c = 0; c < 8; ++c) {
    const float* Op = Opart + (size_t)(base + c) * 4096 + r * 64 + d0;
    #pragma unroll
    for (int d4 = 0; d4 < 4; ++d4) {
      float4 v4 = *(const float4*)(Op + d4 * 4);
      o[d4 * 4 + 0] += v4.x * sc[c];
      o[d4 * 4 + 1] += v4.y * sc[c];
      o[d4 * 4 + 2] += v4.z * sc[c];
      o[d4 * 4 + 3] += v4.w * sc[c];
    }
  }
  const int row = qi * 64 + r;
  float inv = mask[row] / l;
  #pragma unroll
  for (int d = 0; d < 16; ++d)
    outp[(size_t)row * DMODEL + h * 64 + d0 + d] = (__hip_bfloat16)(o[d] * inv);
}

// ---------------- driver ----------------
extern "C" void kernel_launch(void* const* d_in, const int* in_sizes, int n_in,
                              void* d_out, int out_size, void* d_ws, size_t ws_size,
                              hipStream_t stream)
{
  const int*   ids      = (const int*)  d_in[0];
  const float* mask     = (const float*)d_in[1];
  const int*   rand_att = (const int*)  d_in[2];
  const float* emb_word = (const float*)d_in[3];
  const float* emb_pos  = (const float*)d_in[4];
  const float* eg       = (const float*)d_in[5];
  const float* eb       = (const float*)d_in[6];
  const float* Wq = (const float*)d_in[7];
  const float* bq = (const float*)d_in[8];
  const float* Wk = (const float*)d_in[9];
  const float* bk = (const float*)d_in[10];
  const float* Wv = (const float*)d_in[11];
  const float* bv = (const float*)d_in[12];
  const float* Wo = (const float*)d_in[13];
  const float* bo = (const float*)d_in[14];
  const float* ln1g = (const float*)d_in[15];
  const float* ln1b = (const float*)d_in[16];
  const float* W1 = (const float*)d_in[17];
  const float* bf1 = (const float*)d_in[18];
  const float* W2 = (const float*)d_in[19];
  const float* bf2 = (const float*)d_in[20];
  const float* ln2g = (const float*)d_in[21];
  const float* ln2b = (const float*)d_in[22];

  const size_t ND = (size_t)NTOK * DMODEL;
  float* x   = (float*)d_ws;                               // ND f32
  __hip_bfloat16* xb = (__hip_bfloat16*)(x + ND);          // ND bf16
  float* t   = (float*)(xb + ND);                          // ND f32
  __hip_bfloat16* qkvb = (__hip_bfloat16*)(t + ND);        // 3*ND bf16
  __hip_bfloat16* fb_b = qkvb + 3 * ND;                    // NTOK*DFF bf16
  __hip_bfloat16* ab_b = fb_b + (size_t)NTOK * DFF;        // ND bf16
  __hip_bfloat16* wqkvT = ab_b + ND;
  __hip_bfloat16* woT  = wqkvT + (size_t)3 * DMODEL * DMODEL;
  __hip_bfloat16* w1T  = woT  + (size_t)DMODEL * DMODEL;
  __hip_bfloat16* w2T  = w1T  + (size_t)DFF * DMODEL;
  float* biasf = (float*)(w2T + (size_t)DMODEL * DFF);
  float* Mpart = biasf + 3 * DMODEL;
  float* Lpart = Mpart + NHEAD * 2 * 8 * 64;
  float* Opart = Lpart + NHEAD * 2 * 8 * 64;               // 12*2*8*4096 f32

  embed_ln_kernel<<<NTOK, 256, 0, stream>>>(ids, emb_word, emb_pos, eg, eb, x, xb);

  for (int l = 0; l < NLAYER; ++l) {
    const float* Wq_l = Wq + (size_t)l * DMODEL * DMODEL;
    const float* Wk_l = Wk + (size_t)l * DMODEL * DMODEL;
    const float* Wv_l = Wv + (size_t)l * DMODEL * DMODEL;
    const float* Wo_l = Wo + (size_t)l * DMODEL * DMODEL;
    const float* W1_l = W1 + (size_t)l * DMODEL * DFF;
    const float* W2_l = W2 + (size_t)l * DFF * DMODEL;

    dim3 g32(DMODEL / 32, DMODEL / 32);
    transpose_w_kernel<<<g32, 256, 0, stream>>>(Wq_l, wqkvT, DMODEL, DMODEL);
    transpose_w_kernel<<<g32, 256, 0, stream>>>(Wk_l, wqkvT + (size_t)DMODEL * DMODEL, DMODEL, DMODEL);
    transpose_w_kernel<<<g32, 256, 0, stream>>>(Wv_l, wqkvT + (size_t)2 * DMODEL * DMODEL, DMODEL, DMODEL);
    transpose_w_kernel<<<g32, 256, 0, stream>>>(Wo_l, woT, DMODEL, DMODEL);
    transpose_w_kernel<<<dim3(DFF / 32, DMODEL / 32), 256, 0, stream>>>(W1_l, w1T, DMODEL, DFF);
    transpose_w_kernel<<<dim3(DMODEL / 32, DFF / 32), 256, 0, stream>>>(W2_l, w2T, DFF, DMODEL);
    pack_bias_kernel<<<9, 256, 0, stream>>>(bq + (size_t)l * DMODEL, bk + (size_t)l * DMODEL,
                                            bv + (size_t)l * DMODEL, biasf);

    // fused QKV (bf16 out only)
    gemm_bf16_kernel<<<dim3(NTOK / 128, 3 * DMODEL / 128), 256, 0, stream>>>(
        xb, wqkvT, biasf, nullptr, qkvb, DMODEL, 3 * DMODEL, 0);

    attn_kernel<<<dim3(NHEAD, 78), 256, 0, stream>>>(qkvb, mask, rand_att, ab_b,
                                                     Mpart, Lpart, Opart);
    attn_merge_kernel<<<dim3(NHEAD, 2), 256, 0, stream>>>(Mpart, Lpart, Opart, mask, ab_b);

    gemm_bf16_kernel<<<dim3(NTOK / 128, DMODEL / 128), 256, 0, stream>>>(
        ab_b, woT, bo + (size_t)l * DMODEL, t, nullptr, DMODEL, DMODEL, 0);
    add_ln_kernel<<<NTOK, 256, 0, stream>>>(x, t, ln1g + (size_t)l * DMODEL,
                                            ln1b + (size_t)l * DMODEL, x, xb);

    gemm_bf16_kernel<<<dim3(NTOK / 128, DFF / 128), 256, 0, stream>>>(
        xb, w1T, bf1 + (size_t)l * DFF, nullptr, fb_b, DMODEL, DFF, 1);
    gemm_bf16_kernel<<<dim3(NTOK / 128, DMODEL / 128), 256, 0, stream>>>(
        fb_b, w2T, bf2 + (size_t)l * DMODEL, t, nullptr, DFF, DMODEL, 0);
    add_ln_kernel<<<NTOK, 256, 0, stream>>>(x, t, ln2g + (size_t)l * DMODEL,
                                            ln2b + (size_t)l * DMODEL,
                                            (l == NLAYER - 1) ? (float*)d_out : x, xb);
  }
}

// Round 5
// 1095.889 us; speedup vs baseline: 7.8125x; 1.0528x over previous
//
#include <hip/hip_runtime.h>
#include <hip/hip_bf16.h>
#include <math.h>

#define NTOK   4096
#define DMODEL 768
#define NHEAD  12
#define DHEAD  64
#define NLAYER 4
#define DFF    3072
#define NBLK   64
#define NEGC   -10000.0f

using frag8 = __attribute__((ext_vector_type(8))) short;   // 8 bf16
using f32x4 = __attribute__((ext_vector_type(4))) float;

typedef __attribute__((address_space(3))) void       lds_void;
typedef const __attribute__((address_space(1))) void gbl_void;

__device__ __forceinline__ void gload_lds16(const void* g, void* l) {
  __builtin_amdgcn_global_load_lds((gbl_void*)g, (lds_void*)l, 16, 0, 0);
}

// ---------------- block-wide sum over 256 threads ----------------
__device__ __forceinline__ float block_sum256(float v) {
  __shared__ float tmp[4];
  #pragma unroll
  for (int o = 32; o > 0; o >>= 1) v += __shfl_down(v, o, 64);
  __syncthreads();
  if ((threadIdx.x & 63) == 0) tmp[threadIdx.x >> 6] = v;
  __syncthreads();
  return tmp[0] + tmp[1] + tmp[2] + tmp[3];
}

// ---------------- embedding + layernorm (emit fp32 + bf16) ----------------
__global__ __launch_bounds__(256) void embed_ln_kernel(
    const int* __restrict__ ids, const float* __restrict__ emb_word,
    const float* __restrict__ emb_pos, const float* __restrict__ g,
    const float* __restrict__ b, float* __restrict__ x,
    __hip_bfloat16* __restrict__ xb)
{
  const int n = blockIdx.x;
  const int tid = threadIdx.x;
  const int id = ids[n];
  float v[3];
  #pragma unroll
  for (int j = 0; j < 3; ++j) {
    int d = tid + j * 256;
    v[j] = emb_word[(size_t)id * DMODEL + d] + emb_pos[(size_t)n * DMODEL + d];
  }
  float mu = block_sum256(v[0] + v[1] + v[2]) * (1.0f / DMODEL);
  float var = 0.f;
  #pragma unroll
  for (int j = 0; j < 3; ++j) { float t = v[j] - mu; var += t * t; }
  var = block_sum256(var) * (1.0f / DMODEL);
  float rs = rsqrtf(var + 1e-5f);
  #pragma unroll
  for (int j = 0; j < 3; ++j) {
    int d = tid + j * 256;
    float o = (v[j] - mu) * rs * g[d] + b[d];
    x[(size_t)n * DMODEL + d] = o;
    xb[(size_t)n * DMODEL + d] = (__hip_bfloat16)o;
  }
}

// ---------------- residual + Σ split-K partials + bias, then LN ----------------
__global__ __launch_bounds__(256) void add_ln_red_kernel(
    const float* __restrict__ xin, const float* __restrict__ P, size_t ps,
    int nparts, const float* __restrict__ bias2,
    const float* __restrict__ g, const float* __restrict__ b,
    float* __restrict__ dst, __hip_bfloat16* __restrict__ dstb)
{
  const int n = blockIdx.x;
  const int tid = threadIdx.x;
  float v[3];
  #pragma unroll
  for (int j = 0; j < 3; ++j) {
    int d = tid + j * 256;
    float s = xin[(size_t)n * DMODEL + d] + bias2[d];
    for (int z = 0; z < nparts; ++z)
      s += P[(size_t)z * ps + (size_t)n * DMODEL + d];
    v[j] = s;
  }
  float mu = block_sum256(v[0] + v[1] + v[2]) * (1.0f / DMODEL);
  float var = 0.f;
  #pragma unroll
  for (int j = 0; j < 3; ++j) { float t = v[j] - mu; var += t * t; }
  var = block_sum256(var) * (1.0f / DMODEL);
  float rs = rsqrtf(var + 1e-5f);
  #pragma unroll
  for (int j = 0; j < 3; ++j) {
    int d = tid + j * 256;
    float ov = (v[j] - mu) * rs * g[d] + b[d];
    dst[(size_t)n * DMODEL + d] = ov;
    dstb[(size_t)n * DMODEL + d] = (__hip_bfloat16)ov;
  }
}

// ---------------- weight convert + transpose: W(K,N) fp32 -> WT(N,K) bf16 ----------------
__global__ __launch_bounds__(256) void transpose_w_kernel(
    const float* __restrict__ W, __hip_bfloat16* __restrict__ WT, int K, int N)
{
  __shared__ float tile[32][33];
  const int n0 = blockIdx.x * 32;
  const int k0 = blockIdx.y * 32;
  const int c = threadIdx.x & 31;
  const int r0 = threadIdx.x >> 5;
  #pragma unroll
  for (int i = 0; i < 4; ++i) {
    int r = r0 + i * 8;
    tile[r][c] = W[(size_t)(k0 + r) * N + n0 + c];
  }
  __syncthreads();
  #pragma unroll
  for (int i = 0; i < 4; ++i) {
    int r = r0 + i * 8;
    WT[(size_t)(n0 + r) * K + k0 + c] = (__hip_bfloat16)tile[c][r];
  }
}

// ---------------- pack fused QKV bias (2304) ----------------
__global__ __launch_bounds__(256) void pack_bias_kernel(
    const float* __restrict__ bq, const float* __restrict__ bk,
    const float* __restrict__ bv, float* __restrict__ dst)
{
  int t = blockIdx.x * 256 + threadIdx.x;
  if (t < 3 * DMODEL)
    dst[t] = (t < DMODEL) ? bq[t] : (t < 2 * DMODEL ? bk[t - DMODEL] : bv[t - 2 * DMODEL]);
}

// ---------------- bf16 MFMA GEMM, double-buffered, optional split-K ----------------
// C = A(M x lda-rows) @ BT(N x ldb-rows)^T.  128x128 tile, BK=32, 256 thr,
// 4 waves 2x2 of 64x64, 16x16x32 MFMA. blockIdx.z = K-part (offset z*Kpart,
// output to Cf + z*cfStride). One barrier per K-step; next tile's async
// global_load_lds issued right after the barrier.
__global__ __launch_bounds__(256) void gemm_bf16_kernel(
    const __hip_bfloat16* __restrict__ A, int lda,
    const __hip_bfloat16* __restrict__ BT, int ldb,
    const float* __restrict__ bias,
    float* __restrict__ Cf, size_t cfStride,
    __hip_bfloat16* __restrict__ Cb,
    int Kpart, int ldC, int do_gelu)
{
  __shared__ __hip_bfloat16 Als[2][128 * 32];
  __shared__ __hip_bfloat16 Bls[2][128 * 32];
  const int tid = threadIdx.x;
  const int bm = blockIdx.x * 128;
  const int bn = blockIdx.y * 128;
  const int z  = blockIdx.z;
  const int koff = z * Kpart;

  const int wave = tid >> 6, lane = tid & 63;
  const int wm = (wave >> 1) * 64, wn = (wave & 1) * 64;
  const int lm = lane & 15, quad = lane >> 4;

  const int r0 = (0 * 4 + wave) * 16 + (lane >> 2);
  const int r1 = (1 * 4 + wave) * 16 + (lane >> 2);
  const int kc = (lane & 3) * 8;

  const __hip_bfloat16* Ar0 = A  + (size_t)(bm + r0) * lda + koff + kc;
  const __hip_bfloat16* Ar1 = A  + (size_t)(bm + r1) * lda + koff + kc;
  const __hip_bfloat16* Br0 = BT + (size_t)(bn + r0) * ldb + koff + kc;
  const __hip_bfloat16* Br1 = BT + (size_t)(bn + r1) * ldb + koff + kc;

  f32x4 acc[4][4];
  #pragma unroll
  for (int i = 0; i < 4; ++i)
    #pragma unroll
    for (int j = 0; j < 4; ++j)
      acc[i][j] = (f32x4){0.f, 0.f, 0.f, 0.f};

  gload_lds16(Ar0, &Als[0][r0 * 32 + kc]);
  gload_lds16(Ar1, &Als[0][r1 * 32 + kc]);
  gload_lds16(Br0, &Bls[0][r0 * 32 + kc]);
  gload_lds16(Br1, &Bls[0][r1 * 32 + kc]);

  int p = 0;
  for (int k0 = 0; k0 < Kpart; k0 += 32, p ^= 1) {
    __syncthreads();
    const int kn = k0 + 32;
    if (kn < Kpart) {
      gload_lds16(Ar0 + kn, &Als[p ^ 1][r0 * 32 + kc]);
      gload_lds16(Ar1 + kn, &Als[p ^ 1][r1 * 32 + kc]);
      gload_lds16(Br0 + kn, &Bls[p ^ 1][r0 * 32 + kc]);
      gload_lds16(Br1 + kn, &Bls[p ^ 1][r1 * 32 + kc]);
    }
    frag8 afr[4], bfr[4];
    #pragma unroll
    for (int t = 0; t < 4; ++t) {
      afr[t] = *(const frag8*)(&Als[p][(wm + t * 16 + lm) * 32 + quad * 8]);
      bfr[t] = *(const frag8*)(&Bls[p][(wn + t * 16 + lm) * 32 + quad * 8]);
    }
    #pragma unroll
    for (int mt = 0; mt < 4; ++mt)
      #pragma unroll
      for (int nt = 0; nt < 4; ++nt)
        acc[mt][nt] = __builtin_amdgcn_mfma_f32_16x16x32_bf16(
            afr[mt], bfr[nt], acc[mt][nt], 0, 0, 0);
  }

  float* Cfz = Cf ? Cf + (size_t)z * cfStride : nullptr;
  #pragma unroll
  for (int mt = 0; mt < 4; ++mt)
    #pragma unroll
    for (int nt = 0; nt < 4; ++nt)
      #pragma unroll
      for (int r = 0; r < 4; ++r) {
        int row = bm + wm + mt * 16 + quad * 4 + r;
        int col = bn + wn + nt * 16 + lm;
        float v = acc[mt][nt][r];
        if (bias) v += bias[col];
        if (do_gelu) v = 0.5f * v * (1.f + erff(v * 0.70710678118654752f));
        if (Cfz) Cfz[(size_t)row * ldC + col] = v;
        if (Cb) Cb[(size_t)row * ldC + col] = (__hip_bfloat16)v;
      }
}

// ---------------- BigBird attention: bf16 MFMA, register online-softmax ----------------
__global__ __launch_bounds__(256) void attn_kernel(
    const __hip_bfloat16* __restrict__ qkvb, const float* __restrict__ mask,
    const int* __restrict__ rand_attn, __hip_bfloat16* __restrict__ outp,
    float* __restrict__ Mpart, float* __restrict__ Lpart, float* __restrict__ Opart)
{
  const int h = blockIdx.x;
  const int item = blockIdx.y;
  const int tid = threadIdx.x;

  int qi, chunk;
  if (item < 8)       { qi = 0;        chunk = item; }
  else if (item < 70) { qi = item - 7; chunk = -1; }
  else                { qi = 63;       chunk = item - 70; }

  __shared__ __hip_bfloat16 Qs[64 * 72];
  __shared__ __hip_bfloat16 Ks[64 * 72];
  __shared__ __hip_bfloat16 VTs[64 * 72];
  __shared__ __hip_bfloat16 Ps[64 * 72];
  __shared__ int slist[8];
  __shared__ int snb;

  const __hip_bfloat16* qg = qkvb;
  const __hip_bfloat16* kg = qkvb + DMODEL;
  const __hip_bfloat16* vg = qkvb + 2 * DMODEL;
  const int ldq = 3 * DMODEL;

  const int wave = tid >> 6, lane = tid & 63;
  const int wm = wave * 16;
  const int lm = lane & 15, quad = lane >> 4;

  {
    int r = tid >> 2, c0 = (tid & 3) * 16;
    const __hip_bfloat16* qp = qg + (size_t)(qi * 64 + r) * ldq + h * 64 + c0;
    uint4 a = *(const uint4*)qp;
    uint4 b = *(const uint4*)(qp + 8);
    *(uint4*)(Qs + r * 72 + c0) = a;
    *(uint4*)(Qs + r * 72 + c0 + 8) = b;
  }
  if (tid == 0) {
    if (chunk >= 0) {
      for (int j = 0; j < 8; ++j) slist[j] = chunk * 8 + j;
      snb = 8;
    } else {
      const int* ra = rand_attn + ((size_t)h * 62 + (qi - 1)) * 3;
      if (qi == 1)       { slist[0] = 0; slist[1] = 1;  slist[2] = 2;  slist[3] = 63; }
      else if (qi == 62) { slist[0] = 0; slist[1] = 61; slist[2] = 62; slist[3] = 63; }
      else               { slist[0] = 0; slist[1] = qi - 1; slist[2] = qi; slist[3] = qi + 1; }
      slist[4] = ra[0]; slist[5] = ra[1]; slist[6] = ra[2];
      int nb = 7;
      if (qi >= 2 && qi <= 61) { slist[7] = 63; nb = 8; }
      snb = nb;
    }
  }
  __syncthreads();
  const int nb = snb;

  frag8 aq0 = *(const frag8*)(Qs + (wm + lm) * 72 + quad * 8);
  frag8 aq1 = *(const frag8*)(Qs + (wm + lm) * 72 + 32 + quad * 8);

  float mold[4], lsum[4];
  #pragma unroll
  for (int r = 0; r < 4; ++r) { mold[r] = -1e30f; lsum[r] = 0.f; }
  f32x4 oacc[4];
  #pragma unroll
  for (int t = 0; t < 4; ++t) oacc[t] = (f32x4){0.f, 0.f, 0.f, 0.f};

  const int sr = tid >> 2, sc0 = (tid & 3) * 16;

  for (int bi = 0; bi < nb; ++bi) {
    const int kb = slist[bi];
    const __hip_bfloat16* kp = kg + (size_t)(kb * 64 + sr) * ldq + h * 64 + sc0;
    const __hip_bfloat16* vp = vg + (size_t)(kb * 64 + sr) * ldq + h * 64 + sc0;
    uint4 kv0 = *(const uint4*)kp;
    uint4 kv1 = *(const uint4*)(kp + 8);
    uint4 vv0 = *(const uint4*)vp;
    uint4 vv1 = *(const uint4*)(vp + 8);
    float msk[4];
    #pragma unroll
    for (int t = 0; t < 4; ++t) msk[t] = mask[kb * 64 + t * 16 + lm];

    __syncthreads();
    *(uint4*)(Ks + sr * 72 + sc0) = kv0;
    *(uint4*)(Ks + sr * 72 + sc0 + 8) = kv1;
    {
      union { uint4 u[2]; __hip_bfloat16 h16[16]; } vu;
      vu.u[0] = vv0; vu.u[1] = vv1;
      #pragma unroll
      for (int j = 0; j < 16; ++j)
        VTs[(sc0 + j) * 72 + sr] = vu.h16[j];
    }
    __syncthreads();

    f32x4 sacc[4];
    #pragma unroll
    for (int t = 0; t < 4; ++t) sacc[t] = (f32x4){0.f, 0.f, 0.f, 0.f};
    #pragma unroll
    for (int t = 0; t < 4; ++t) {
      frag8 bk0 = *(const frag8*)(Ks + (t * 16 + lm) * 72 + quad * 8);
      frag8 bk1 = *(const frag8*)(Ks + (t * 16 + lm) * 72 + 32 + quad * 8);
      sacc[t] = __builtin_amdgcn_mfma_f32_16x16x32_bf16(aq0, bk0, sacc[t], 0, 0, 0);
      sacc[t] = __builtin_amdgcn_mfma_f32_16x16x32_bf16(aq1, bk1, sacc[t], 0, 0, 0);
    }

    float xs[4][4];
    #pragma unroll
    for (int t = 0; t < 4; ++t)
      #pragma unroll
      for (int r = 0; r < 4; ++r)
        xs[t][r] = sacc[t][r] * 0.125f + (1.f - msk[t]) * NEGC;

    float al[4], psum[4];
    #pragma unroll
    for (int r = 0; r < 4; ++r) {
      float rm = fmaxf(fmaxf(xs[0][r], xs[1][r]), fmaxf(xs[2][r], xs[3][r]));
      rm = fmaxf(rm, __shfl_xor(rm, 1, 64));
      rm = fmaxf(rm, __shfl_xor(rm, 2, 64));
      rm = fmaxf(rm, __shfl_xor(rm, 4, 64));
      rm = fmaxf(rm, __shfl_xor(rm, 8, 64));
      float mnew = fmaxf(mold[r], rm);
      al[r] = __expf(mold[r] - mnew);
      float s = 0.f;
      #pragma unroll
      for (int t = 0; t < 4; ++t) {
        float p = __expf(xs[t][r] - mnew);
        xs[t][r] = p;
        s += p;
      }
      s += __shfl_xor(s, 1, 64);
      s += __shfl_xor(s, 2, 64);
      s += __shfl_xor(s, 4, 64);
      s += __shfl_xor(s, 8, 64);
      psum[r] = s;
      mold[r] = mnew;
    }
    #pragma unroll
    for (int r = 0; r < 4; ++r) lsum[r] = lsum[r] * al[r] + psum[r];
    #pragma unroll
    for (int t = 0; t < 4; ++t)
      #pragma unroll
      for (int r = 0; r < 4; ++r)
        oacc[t][r] *= al[r];

    #pragma unroll
    for (int t = 0; t < 4; ++t)
      #pragma unroll
      for (int r = 0; r < 4; ++r)
        Ps[(wm + quad * 4 + r) * 72 + t * 16 + lm] = (__hip_bfloat16)xs[t][r];

    frag8 ap0 = *(const frag8*)(Ps + (wm + lm) * 72 + quad * 8);
    frag8 ap1 = *(const frag8*)(Ps + (wm + lm) * 72 + 32 + quad * 8);
    #pragma unroll
    for (int t = 0; t < 4; ++t) {
      frag8 bv0 = *(const frag8*)(VTs + (t * 16 + lm) * 72 + quad * 8);
      frag8 bv1 = *(const frag8*)(VTs + (t * 16 + lm) * 72 + 32 + quad * 8);
      oacc[t] = __builtin_amdgcn_mfma_f32_16x16x32_bf16(ap0, bv0, oacc[t], 0, 0, 0);
      oacc[t] = __builtin_amdgcn_mfma_f32_16x16x32_bf16(ap1, bv1, oacc[t], 0, 0, 0);
    }
  }

  if (chunk < 0) {
    #pragma unroll
    for (int r = 0; r < 4; ++r) {
      int row = qi * 64 + wm + quad * 4 + r;
      float sc2 = mask[row] / lsum[r];
      #pragma unroll
      for (int t = 0; t < 4; ++t)
        outp[(size_t)row * DMODEL + h * 64 + t * 16 + lm] =
            (__hip_bfloat16)(oacc[t][r] * sc2);
    }
  } else {
    const int idx = (h * 2 + (qi == 63 ? 1 : 0)) * 8 + chunk;
    #pragma unroll
    for (int r = 0; r < 4; ++r) {
      int row = wm + quad * 4 + r;
      #pragma unroll
      for (int t = 0; t < 4; ++t)
        Opart[(size_t)idx * 4096 + row * 64 + t * 16 + lm] = oacc[t][r];
      if (lm == 0) {
        Mpart[idx * 64 + row] = mold[r];
        Lpart[idx * 64 + row] = lsum[r];
      }
    }
  }
}

// ---------------- merge partials for global rows (qi 0 and 63) ----------------
__global__ __launch_bounds__(256) void attn_merge_kernel(
    const float* __restrict__ Mpart, const float* __restrict__ Lpart,
    const float* __restrict__ Opart, const float* __restrict__ mask,
    __hip_bfloat16* __restrict__ outp)
{
  const int h = blockIdx.x, side = blockIdx.y;
  const int qi = side ? 63 : 0;
  const int tid = threadIdx.x;
  const int r = tid >> 2;
  const int d0 = (tid & 3) * 16;
  const int base = (h * 2 + side) * 8;

  float mv[8], m = -1e30f;
  #pragma unroll
  for (int c = 0; c < 8; ++c) { mv[c] = Mpart[(base + c) * 64 + r]; m = fmaxf(m, mv[c]); }
  float sc[8], l = 0.f;
  #pragma unroll
  for (int c = 0; c < 8; ++c) {
    sc[c] = __expf(mv[c] - m);
    l += Lpart[(base + c) * 64 + r] * sc[c];
  }
  float o[16];
  #pragma unroll
  for (int d = 0; d < 16; ++d) o[d] = 0.f;
  #pragma unroll
  for (int c = 0; c < 8; ++c) {
    const float* Op = Opart + (size_t)(base + c) * 4096 + r * 64 + d0;
    #pragma unroll
    for (int d4 = 0; d4 < 4; ++d4) {
      float4 v4 = *(const float4*)(Op + d4 * 4);
      o[d4 * 4 + 0] += v4.x * sc[c];
      o[d4 * 4 + 1] += v4.y * sc[c];
      o[d4 * 4 + 2] += v4.z * sc[c];
      o[d4 * 4 + 3] += v4.w * sc[c];
    }
  }
  const int row = qi * 64 + r;
  float inv = mask[row] / l;
  #pragma unroll
  for (int d = 0; d < 16; ++d)
    outp[(size_t)row * DMODEL + h * 64 + d0 + d] = (__hip_bfloat16)(o[d] * inv);
}

// ---------------- driver ----------------
extern "C" void kernel_launch(void* const* d_in, const int* in_sizes, int n_in,
                              void* d_out, int out_size, void* d_ws, size_t ws_size,
                              hipStream_t stream)
{
  const int*   ids      = (const int*)  d_in[0];
  const float* mask     = (const float*)d_in[1];
  const int*   rand_att = (const int*)  d_in[2];
  const float* emb_word = (const float*)d_in[3];
  const float* emb_pos  = (const float*)d_in[4];
  const float* eg       = (const float*)d_in[5];
  const float* eb       = (const float*)d_in[6];
  const float* Wq = (const float*)d_in[7];
  const float* bq = (const float*)d_in[8];
  const float* Wk = (const float*)d_in[9];
  const float* bk = (const float*)d_in[10];
  const float* Wv = (const float*)d_in[11];
  const float* bv = (const float*)d_in[12];
  const float* Wo = (const float*)d_in[13];
  const float* bo = (const float*)d_in[14];
  const float* ln1g = (const float*)d_in[15];
  const float* ln1b = (const float*)d_in[16];
  const float* W1 = (const float*)d_in[17];
  const float* bf1 = (const float*)d_in[18];
  const float* W2 = (const float*)d_in[19];
  const float* bf2 = (const float*)d_in[20];
  const float* ln2g = (const float*)d_in[21];
  const float* ln2b = (const float*)d_in[22];

  const size_t ND = (size_t)NTOK * DMODEL;
  float* x   = (float*)d_ws;                               // ND f32
  __hip_bfloat16* xb = (__hip_bfloat16*)(x + ND);          // ND bf16
  float* P   = (float*)(xb + ND);                          // 3*ND f32 split-K partials
  __hip_bfloat16* qkvb = (__hip_bfloat16*)(P + 3 * ND);    // 3*ND bf16
  __hip_bfloat16* fb_b = qkvb + 3 * ND;                    // NTOK*DFF bf16
  __hip_bfloat16* ab_b = fb_b + (size_t)NTOK * DFF;        // ND bf16
  __hip_bfloat16* wqkvT = ab_b + ND;
  __hip_bfloat16* woT  = wqkvT + (size_t)3 * DMODEL * DMODEL;
  __hip_bfloat16* w1T  = woT  + (size_t)DMODEL * DMODEL;
  __hip_bfloat16* w2T  = w1T  + (size_t)DFF * DMODEL;
  float* biasf = (float*)(w2T + (size_t)DMODEL * DFF);
  float* Mpart = biasf + 3 * DMODEL;
  float* Lpart = Mpart + NHEAD * 2 * 8 * 64;
  float* Opart = Lpart + NHEAD * 2 * 8 * 64;               // 12*2*8*4096 f32

  embed_ln_kernel<<<NTOK, 256, 0, stream>>>(ids, emb_word, emb_pos, eg, eb, x, xb);

  for (int l = 0; l < NLAYER; ++l) {
    const float* Wq_l = Wq + (size_t)l * DMODEL * DMODEL;
    const float* Wk_l = Wk + (size_t)l * DMODEL * DMODEL;
    const float* Wv_l = Wv + (size_t)l * DMODEL * DMODEL;
    const float* Wo_l = Wo + (size_t)l * DMODEL * DMODEL;
    const float* W1_l = W1 + (size_t)l * DMODEL * DFF;
    const float* W2_l = W2 + (size_t)l * DFF * DMODEL;

    dim3 g32(DMODEL / 32, DMODEL / 32);
    transpose_w_kernel<<<g32, 256, 0, stream>>>(Wq_l, wqkvT, DMODEL, DMODEL);
    transpose_w_kernel<<<g32, 256, 0, stream>>>(Wk_l, wqkvT + (size_t)DMODEL * DMODEL, DMODEL, DMODEL);
    transpose_w_kernel<<<g32, 256, 0, stream>>>(Wv_l, wqkvT + (size_t)2 * DMODEL * DMODEL, DMODEL, DMODEL);
    transpose_w_kernel<<<g32, 256, 0, stream>>>(Wo_l, woT, DMODEL, DMODEL);
    transpose_w_kernel<<<dim3(DFF / 32, DMODEL / 32), 256, 0, stream>>>(W1_l, w1T, DMODEL, DFF);
    transpose_w_kernel<<<dim3(DMODEL / 32, DFF / 32), 256, 0, stream>>>(W2_l, w2T, DFF, DMODEL);
    pack_bias_kernel<<<9, 256, 0, stream>>>(bq + (size_t)l * DMODEL, bk + (size_t)l * DMODEL,
                                            bv + (size_t)l * DMODEL, biasf);

    // fused QKV (bf16 out only)
    gemm_bf16_kernel<<<dim3(NTOK / 128, 3 * DMODEL / 128, 1), 256, 0, stream>>>(
        xb, DMODEL, wqkvT, DMODEL, biasf, nullptr, 0, qkvb, DMODEL, 3 * DMODEL, 0);

    attn_kernel<<<dim3(NHEAD, 78), 256, 0, stream>>>(qkvb, mask, rand_att, ab_b,
                                                     Mpart, Lpart, Opart);
    attn_merge_kernel<<<dim3(NHEAD, 2), 256, 0, stream>>>(Mpart, Lpart, Opart, mask, ab_b);

    // Wo: split-K=2 (K=768 -> 2x384), partials into P
    gemm_bf16_kernel<<<dim3(NTOK / 128, DMODEL / 128, 2), 256, 0, stream>>>(
        ab_b, DMODEL, woT, DMODEL, nullptr, P, ND, nullptr, DMODEL / 2, DMODEL, 0);
    add_ln_red_kernel<<<NTOK, 256, 0, stream>>>(x, P, ND, 2, bo + (size_t)l * DMODEL,
                                                ln1g + (size_t)l * DMODEL,
                                                ln1b + (size_t)l * DMODEL, x, xb);

    // FFN1 (gelu, bf16 out)
    gemm_bf16_kernel<<<dim3(NTOK / 128, DFF / 128, 1), 256, 0, stream>>>(
        xb, DMODEL, w1T, DMODEL, bf1 + (size_t)l * DFF, nullptr, 0, fb_b, DMODEL, DFF, 1);

    // FFN2: split-K=3 (K=3072 -> 3x1024), partials into P
    gemm_bf16_kernel<<<dim3(NTOK / 128, DMODEL / 128, 3), 256, 0, stream>>>(
        fb_b, DFF, w2T, DFF, nullptr, P, ND, nullptr, DFF / 3, DMODEL, 0);
    add_ln_red_kernel<<<NTOK, 256, 0, stream>>>(x, P, ND, 3, bf2 + (size_t)l * DMODEL,
                                                ln2g + (size_t)l * DMODEL,
                                                ln2b + (size_t)l * DMODEL,
                                                (l == NLAYER - 1) ? (float*)d_out : x, xb);
  }
}